// Round 1
// baseline (5744.904 us; speedup 1.0000x reference)
//
#include <hip/hip_runtime.h>
#include <cstddef>

#define NTOK 2048
#define BDIM 4
#define DIM 256
#define NHEAD 4
#define HDIM 64
#define MROWS (BDIM * NTOK)            // 8192
#define NM ((size_t)MROWS * DIM)       // 2,097,152 floats per (B,N,D) buffer

// ---------------------------------------------------------------------------
// GEMM: Y[m][n] = sum_k X[m][k] * W[n][k] + bias[n] (+ res[m][n])
// X: (MROWS, K) row-major with row stride ldx; W: (Ncols, K) row-major.
// Tile 64x64, 256 threads, 4x4 micro-tile per thread, K-step 16.
// ---------------------------------------------------------------------------
__global__ __launch_bounds__(256) void gemm_kernel(
    const float* __restrict__ X, int ldx,
    const float* __restrict__ W,
    const float* __restrict__ bias,
    const float* __restrict__ res, int ldr,
    float* __restrict__ Y, int ldy,
    int K)
{
  __shared__ float Xs[16][68];   // [kk][m]  pad 68 keeps float4 16B alignment
  __shared__ float Ws[16][68];   // [kk][n]
  const int t  = threadIdx.x;
  const int m0 = blockIdx.y * 64, n0 = blockIdx.x * 64;
  const int tx = t & 15, ty = t >> 4;
  const int lj = t >> 2, lk = (t & 3) << 2;

  float acc[4][4] = {};
  for (int k0 = 0; k0 < K; k0 += 16) {
    float4 xv = *(const float4*)(X + (size_t)(m0 + lj) * ldx + k0 + lk);
    float4 wv = *(const float4*)(W + (size_t)(n0 + lj) * K + k0 + lk);
    Xs[lk + 0][lj] = xv.x; Xs[lk + 1][lj] = xv.y;
    Xs[lk + 2][lj] = xv.z; Xs[lk + 3][lj] = xv.w;
    Ws[lk + 0][lj] = wv.x; Ws[lk + 1][lj] = wv.y;
    Ws[lk + 2][lj] = wv.z; Ws[lk + 3][lj] = wv.w;
    __syncthreads();
#pragma unroll
    for (int kk = 0; kk < 16; ++kk) {
      float4 xr = *(const float4*)&Xs[kk][ty << 2];
      float4 wr = *(const float4*)&Ws[kk][tx << 2];
      acc[0][0] += xr.x * wr.x; acc[0][1] += xr.x * wr.y;
      acc[0][2] += xr.x * wr.z; acc[0][3] += xr.x * wr.w;
      acc[1][0] += xr.y * wr.x; acc[1][1] += xr.y * wr.y;
      acc[1][2] += xr.y * wr.z; acc[1][3] += xr.y * wr.w;
      acc[2][0] += xr.z * wr.x; acc[2][1] += xr.z * wr.y;
      acc[2][2] += xr.z * wr.z; acc[2][3] += xr.z * wr.w;
      acc[3][0] += xr.w * wr.x; acc[3][1] += xr.w * wr.y;
      acc[3][2] += xr.w * wr.z; acc[3][3] += xr.w * wr.w;
    }
    __syncthreads();
  }
#pragma unroll
  for (int i = 0; i < 4; ++i) {
    const int row = m0 + (ty << 2) + i;
    const int col = n0 + (tx << 2);
    float4 o;
    o.x = acc[i][0] + bias[col + 0];
    o.y = acc[i][1] + bias[col + 1];
    o.z = acc[i][2] + bias[col + 2];
    o.w = acc[i][3] + bias[col + 3];
    if (res) {
      const float* rp = res + (size_t)row * ldr + col;
      o.x += rp[0]; o.y += rp[1]; o.z += rp[2]; o.w += rp[3];
    }
    *(float4*)(Y + (size_t)row * ldy + col) = o;
  }
}

// ---------------------------------------------------------------------------
// RoPE + repack: qkv (M,768) with col = h*192 + hd*3 + {0:q,1:k,2:v}
// -> Q,K (rope-applied), V in (M, 256) "unheads" layout col = h*64+hd.
// enc: (2, B, 1, N, 64): cos at [m*64+hd], sin at [B*N*64 + m*64+hd].
// One thread per (m, h, pair i).
// ---------------------------------------------------------------------------
__global__ __launch_bounds__(256) void rope_repack_kernel(
    const float* __restrict__ qkv, const float* __restrict__ enc,
    float* __restrict__ Q, float* __restrict__ K, float* __restrict__ V)
{
  const int idx = blockIdx.x * blockDim.x + threadIdx.x;  // < M*4*32
  const int i = idx & 31;
  const int h = (idx >> 5) & 3;
  const int m = idx >> 7;
  const float* src = qkv + (size_t)m * 768 + h * 192 + i * 6;
  const float q0 = src[0], k0 = src[1], v0 = src[2];
  const float q1 = src[3], k1 = src[4], v1 = src[5];
  const float c = enc[(size_t)m * 64 + 2 * i];
  const float s = enc[(size_t)BDIM * NTOK * 64 + (size_t)m * 64 + 2 * i];
  const size_t o = (size_t)m * 256 + h * 64 + 2 * i;
  Q[o]     = q0 * c - q1 * s;
  Q[o + 1] = q1 * c + q0 * s;
  K[o]     = k0 * c - k1 * s;
  K[o + 1] = k1 * c + k0 * s;
  V[o]     = v0;
  V[o + 1] = v1;
}

// ---------------------------------------------------------------------------
// Flash attention, fp32. Q,K,V,O all (B,N,D) with head subspace col=h*64+d.
// Block = 256 threads = 4 waves; wave w handles query row q0+w.
// K tile stored transposed Ks[d][j] (score reads stride-1 over lanes=j);
// V tile direct Vs[j][d]    (accum reads stride-1 over lanes=d).
// scale = HD^-0.5 = 0.125 (cross pre-scale folded in).
// ---------------------------------------------------------------------------
__global__ __launch_bounds__(256) void attn_kernel(
    const float* __restrict__ Q, const float* __restrict__ K,
    const float* __restrict__ V, float* __restrict__ O)
{
  __shared__ float Ks[64][68];
  __shared__ float Vs[64][68];
  __shared__ float qs[4][64];
  __shared__ float ps[4][64];
  const int b = blockIdx.z, h = blockIdx.y;
  const int t = threadIdx.x, lane = t & 63, w = t >> 6;
  const int qi = blockIdx.x * 4 + w;
  const size_t rowbase = (size_t)(b * NTOK + qi) * DIM + h * 64;
  qs[w][lane] = Q[rowbase + lane];

  float m = -1e30f, l = 0.f, acc = 0.f;
  const int j = t >> 2;
  const int cb = (t & 3) * 16;
  for (int k0 = 0; k0 < NTOK; k0 += 64) {
    __syncthreads();   // all waves done with previous tile
    const float* Krow = K + (size_t)(b * NTOK + k0 + j) * DIM + h * 64;
    const float* Vrow = V + (size_t)(b * NTOK + k0 + j) * DIM + h * 64;
#pragma unroll
    for (int i = 0; i < 4; ++i) {
      float4 kv = *(const float4*)(Krow + cb + i * 4);
      Ks[cb + i * 4 + 0][j] = kv.x;
      Ks[cb + i * 4 + 1][j] = kv.y;
      Ks[cb + i * 4 + 2][j] = kv.z;
      Ks[cb + i * 4 + 3][j] = kv.w;
      *(float4*)&Vs[j][cb + i * 4] = *(const float4*)(Vrow + cb + i * 4);
    }
    __syncthreads();
    // score: lane = key index within tile
    float s = 0.f;
#pragma unroll
    for (int d = 0; d < 64; ++d) s += qs[w][d] * Ks[d][lane];
    s *= 0.125f;
    float tm = s;
#pragma unroll
    for (int off = 32; off; off >>= 1) tm = fmaxf(tm, __shfl_xor(tm, off));
    const float mn = fmaxf(m, tm);
    const float p = __expf(s - mn);
    const float alpha = __expf(m - mn);
    float tl = p;
#pragma unroll
    for (int off = 32; off; off >>= 1) tl += __shfl_xor(tl, off);
    l = l * alpha + tl;
    m = mn;
    ps[w][lane] = p;
    // accumulate: lane = head dim
    float a = 0.f;
#pragma unroll
    for (int jj = 0; jj < 64; ++jj) a += ps[w][jj] * Vs[jj][lane];
    acc = acc * alpha + a;
  }
  O[rowbase + lane] = acc / l;
}

// ---------------------------------------------------------------------------
// LayerNorm (eps 1e-5) + exact GELU, in place. Row length 512.
// One wave per row, 8 elems/lane.
// ---------------------------------------------------------------------------
__global__ __launch_bounds__(256) void ln_gelu_kernel(
    float* __restrict__ Hm, const float* __restrict__ g,
    const float* __restrict__ be)
{
  const int wave = (blockIdx.x * 256 + threadIdx.x) >> 6;
  const int lane = threadIdx.x & 63;
  float* row = Hm + (size_t)wave * 512;
  float x[8];
  float s = 0.f;
#pragma unroll
  for (int i = 0; i < 8; ++i) { x[i] = row[lane + 64 * i]; s += x[i]; }
#pragma unroll
  for (int off = 32; off; off >>= 1) s += __shfl_xor(s, off);
  const float mean = s * (1.f / 512.f);
  float s2 = 0.f;
#pragma unroll
  for (int i = 0; i < 8; ++i) { const float d = x[i] - mean; s2 += d * d; }
#pragma unroll
  for (int off = 32; off; off >>= 1) s2 += __shfl_xor(s2, off);
  const float rstd = rsqrtf(s2 * (1.f / 512.f) + 1e-5f);
#pragma unroll
  for (int i = 0; i < 8; ++i) {
    const int c = lane + 64 * i;
    const float y = (x[i] - mean) * rstd * g[c] + be[c];
    row[c] = 0.5f * y * (1.f + erff(y * 0.70710678118654752f));
  }
}

// cat[:, 0:256] = X  (first half of concat buffer)
__global__ __launch_bounds__(256) void copy_cat_kernel(
    const float* __restrict__ X, float* __restrict__ cat)
{
  const int idx = blockIdx.x * 256 + threadIdx.x;   // < M*64
  const int m = idx >> 6, c = (idx & 63) << 2;
  *(float4*)(cat + (size_t)m * 512 + c) = *(const float4*)(X + (size_t)m * 256 + c);
}

// ---------------------------------------------------------------------------
static inline void launch_gemm(const float* X, int ldx, const float* W,
                               const float* bias, const float* res, int ldr,
                               float* Y, int ldy, int Ncols, int K,
                               hipStream_t s)
{
  dim3 g(Ncols / 64, MROWS / 64);
  hipLaunchKernelGGL(gemm_kernel, g, dim3(256), 0, s,
                     X, ldx, W, bias, res, ldr, Y, ldy, K);
}

extern "C" void kernel_launch(void* const* d_in, const int* in_sizes, int n_in,
                              void* d_out, int out_size, void* d_ws, size_t ws_size,
                              hipStream_t stream) {
  const float* desc0  = (const float*)d_in[0];
  const float* desc1  = (const float*)d_in[1];
  const float* enc0   = (const float*)d_in[2];
  const float* enc1   = (const float*)d_in[3];
  const float* s_Wqkv = (const float*)d_in[4];
  const float* s_bqkv = (const float*)d_in[5];
  const float* s_Wout = (const float*)d_in[6];
  const float* s_bout = (const float*)d_in[7];
  const float* s_W1   = (const float*)d_in[8];
  const float* s_b1   = (const float*)d_in[9];
  const float* s_g    = (const float*)d_in[10];
  const float* s_be   = (const float*)d_in[11];
  const float* s_W2   = (const float*)d_in[12];
  const float* s_b2   = (const float*)d_in[13];
  const float* c_Wqk  = (const float*)d_in[14];
  const float* c_bqk  = (const float*)d_in[15];
  const float* c_Wv   = (const float*)d_in[16];
  const float* c_bv   = (const float*)d_in[17];
  const float* c_Wo   = (const float*)d_in[18];
  const float* c_bo   = (const float*)d_in[19];
  const float* c_W1   = (const float*)d_in[20];
  const float* c_b1   = (const float*)d_in[21];
  const float* c_g    = (const float*)d_in[22];
  const float* c_be   = (const float*)d_in[23];
  const float* c_W2   = (const float*)d_in[24];
  const float* c_b2   = (const float*)d_in[25];

  float* ws = (float*)d_ws;
  // arena layout (units of NM floats):
  float* s0   = ws + 0 * NM;           // self-block output 0 (kept for cross)
  float* s1   = ws + 1 * NM;           // self-block output 1
  float* qkv  = ws + 2 * NM;           // (M,768) -> also ctx alias after repack
  float* ctx  = ws + 2 * NM;           // alias of qkv (qkv dead after repack)
  float* qQ   = ws + 5 * NM;           // self Q   / cross v1
  float* qK   = ws + 6 * NM;           // self K   / cross m0
  float* qV   = ws + 7 * NM;           // self V   / cross m1
  float* cat  = ws + 8 * NM;           // (M,512)
  float* hbuf = ws + 10 * NM;          // (M,512)
  // cross aliases:
  float* qk0  = ws + 2 * NM;
  float* qk1  = ws + 3 * NM;
  float* v0   = ws + 4 * NM;
  float* v1   = qQ;
  float* m0   = qK;
  float* m1   = qV;

  float* out0 = (float*)d_out;
  float* out1 = out0 + NM;

  const dim3 attn_grid(NTOK / 4, NHEAD, BDIM);
  const int rope_blocks = (MROWS * 128) / 256;
  const int lng_blocks  = MROWS / 4;
  const int cpy_blocks  = (MROWS * 64) / 256;

  // ---------------- self blocks ----------------
  for (int d = 0; d < 2; ++d) {
    const float* x   = d ? desc1 : desc0;
    const float* enc = d ? enc1 : enc0;
    float* sout      = d ? s1 : s0;

    launch_gemm(x, DIM, s_Wqkv, s_bqkv, nullptr, 0, qkv, 768, 768, DIM, stream);
    hipLaunchKernelGGL(rope_repack_kernel, dim3(rope_blocks), dim3(256), 0, stream,
                       qkv, enc, qQ, qK, qV);
    hipLaunchKernelGGL(attn_kernel, attn_grid, dim3(256), 0, stream, qQ, qK, qV, ctx);
    hipLaunchKernelGGL(copy_cat_kernel, dim3(cpy_blocks), dim3(256), 0, stream, x, cat);
    launch_gemm(ctx, DIM, s_Wout, s_bout, nullptr, 0, cat + 256, 512, DIM, DIM, stream);
    launch_gemm(cat, 512, s_W1, s_b1, nullptr, 0, hbuf, 512, 512, 512, stream);
    hipLaunchKernelGGL(ln_gelu_kernel, dim3(lng_blocks), dim3(256), 0, stream,
                       hbuf, s_g, s_be);
    launch_gemm(hbuf, 512, s_W2, s_b2, x, DIM, sout, DIM, DIM, 512, stream);
  }

  // ---------------- cross block ----------------
  launch_gemm(s0, DIM, c_Wqk, c_bqk, nullptr, 0, qk0, DIM, DIM, DIM, stream);
  launch_gemm(s1, DIM, c_Wqk, c_bqk, nullptr, 0, qk1, DIM, DIM, DIM, stream);
  launch_gemm(s0, DIM, c_Wv,  c_bv,  nullptr, 0, v0,  DIM, DIM, DIM, stream);
  launch_gemm(s1, DIM, c_Wv,  c_bv,  nullptr, 0, v1,  DIM, DIM, DIM, stream);
  // m0 = attn(q=qk0, k=qk1, v=v1); m1 = attn(q=qk1, k=qk0, v=v0)
  hipLaunchKernelGGL(attn_kernel, attn_grid, dim3(256), 0, stream, qk0, qk1, v1, m0);
  hipLaunchKernelGGL(attn_kernel, attn_grid, dim3(256), 0, stream, qk1, qk0, v0, m1);

  for (int d = 0; d < 2; ++d) {
    const float* sd = d ? s1 : s0;
    const float* md = d ? m1 : m0;
    float* outd     = d ? out1 : out0;
    hipLaunchKernelGGL(copy_cat_kernel, dim3(cpy_blocks), dim3(256), 0, stream, sd, cat);
    launch_gemm(md, DIM, c_Wo, c_bo, nullptr, 0, cat + 256, 512, DIM, DIM, stream);
    launch_gemm(cat, 512, c_W1, c_b1, nullptr, 0, hbuf, 512, 512, 512, stream);
    hipLaunchKernelGGL(ln_gelu_kernel, dim3(lng_blocks), dim3(256), 0, stream,
                       hbuf, c_g, c_be);
    launch_gemm(hbuf, 512, c_W2, c_b2, sd, DIM, outd, DIM, DIM, 512, stream);
  }
}

// Round 2
// 1311.181 us; speedup vs baseline: 4.3815x; 4.3815x over previous
//
#include <hip/hip_runtime.h>
#include <cstddef>

#define NTOK 2048
#define BDIM 4
#define DIM 256
#define NHEAD 4
#define HDIM 64
#define MROWS (BDIM * NTOK)            // 8192
#define NM ((size_t)MROWS * DIM)       // 2,097,152 floats per (B,N,D) buffer

typedef __attribute__((ext_vector_type(8))) short short8;
typedef __attribute__((ext_vector_type(4))) float f32x4;

__device__ __forceinline__ unsigned short f2bf(float x) {
  union { float f; unsigned u; } c; c.f = x;
  unsigned r = c.u + 0x7FFFu + ((c.u >> 16) & 1u);
  return (unsigned short)(r >> 16);
}

// ---------------------------------------------------------------------------
// fp32 GEMM (unchanged this round): Y = X @ W^T + bias (+res)
// ---------------------------------------------------------------------------
__global__ __launch_bounds__(256) void gemm_kernel(
    const float* __restrict__ X, int ldx,
    const float* __restrict__ W,
    const float* __restrict__ bias,
    const float* __restrict__ res, int ldr,
    float* __restrict__ Y, int ldy,
    int K)
{
  __shared__ float Xs[16][68];
  __shared__ float Ws[16][68];
  const int t  = threadIdx.x;
  const int m0 = blockIdx.y * 64, n0 = blockIdx.x * 64;
  const int tx = t & 15, ty = t >> 4;
  const int lj = t >> 2, lk = (t & 3) << 2;

  float acc[4][4] = {};
  for (int k0 = 0; k0 < K; k0 += 16) {
    float4 xv = *(const float4*)(X + (size_t)(m0 + lj) * ldx + k0 + lk);
    float4 wv = *(const float4*)(W + (size_t)(n0 + lj) * K + k0 + lk);
    Xs[lk + 0][lj] = xv.x; Xs[lk + 1][lj] = xv.y;
    Xs[lk + 2][lj] = xv.z; Xs[lk + 3][lj] = xv.w;
    Ws[lk + 0][lj] = wv.x; Ws[lk + 1][lj] = wv.y;
    Ws[lk + 2][lj] = wv.z; Ws[lk + 3][lj] = wv.w;
    __syncthreads();
#pragma unroll
    for (int kk = 0; kk < 16; ++kk) {
      float4 xr = *(const float4*)&Xs[kk][ty << 2];
      float4 wr = *(const float4*)&Ws[kk][tx << 2];
      acc[0][0] += xr.x * wr.x; acc[0][1] += xr.x * wr.y;
      acc[0][2] += xr.x * wr.z; acc[0][3] += xr.x * wr.w;
      acc[1][0] += xr.y * wr.x; acc[1][1] += xr.y * wr.y;
      acc[1][2] += xr.y * wr.z; acc[1][3] += xr.y * wr.w;
      acc[2][0] += xr.z * wr.x; acc[2][1] += xr.z * wr.y;
      acc[2][2] += xr.z * wr.z; acc[2][3] += xr.z * wr.w;
      acc[3][0] += xr.w * wr.x; acc[3][1] += xr.w * wr.y;
      acc[3][2] += xr.w * wr.z; acc[3][3] += xr.w * wr.w;
    }
    __syncthreads();
  }
#pragma unroll
  for (int i = 0; i < 4; ++i) {
    const int row = m0 + (ty << 2) + i;
    const int col = n0 + (tx << 2);
    float4 o;
    o.x = acc[i][0] + bias[col + 0];
    o.y = acc[i][1] + bias[col + 1];
    o.z = acc[i][2] + bias[col + 2];
    o.w = acc[i][3] + bias[col + 3];
    if (res) {
      const float* rp = res + (size_t)row * ldr + col;
      o.x += rp[0]; o.y += rp[1]; o.z += rp[2]; o.w += rp[3];
    }
    *(float4*)(Y + (size_t)row * ldy + col) = o;
  }
}

// ---------------------------------------------------------------------------
// RoPE + repack. qkv (M,768) col = h*192 + hd*3 + {q,k,v}.
// Writes Qh, Kh bf16 head-major (B,H,N,64); V fp32 unheads (B,N,256).
// ---------------------------------------------------------------------------
__global__ __launch_bounds__(256) void rope_repack_kernel(
    const float* __restrict__ qkv, const float* __restrict__ enc,
    unsigned short* __restrict__ Qh, unsigned short* __restrict__ Kh,
    float* __restrict__ V)
{
  const int idx = blockIdx.x * blockDim.x + threadIdx.x;  // < M*4*32
  const int i = idx & 31;
  const int h = (idx >> 5) & 3;
  const int m = idx >> 7;
  const int b = m / NTOK, n = m % NTOK;
  const float* src = qkv + (size_t)m * 768 + h * 192 + i * 6;
  const float q0 = src[0], k0 = src[1], v0 = src[2];
  const float q1 = src[3], k1 = src[4], v1 = src[5];
  const float c = enc[(size_t)m * 64 + 2 * i];
  const float s = enc[(size_t)BDIM * NTOK * 64 + (size_t)m * 64 + 2 * i];
  const float qa = q0 * c - q1 * s, qb = q1 * c + q0 * s;
  const float ka = k0 * c - k1 * s, kb = k1 * c + k0 * s;
  const size_t oh = ((size_t)(b * NHEAD + h) * NTOK + n) * 64 + 2 * i;
  *(unsigned*)(Qh + oh) = (unsigned)f2bf(qa) | ((unsigned)f2bf(qb) << 16);
  *(unsigned*)(Kh + oh) = (unsigned)f2bf(ka) | ((unsigned)f2bf(kb) << 16);
  const size_t ov = (size_t)m * 256 + h * 64 + 2 * i;
  V[ov] = v0; V[ov + 1] = v1;
}

// fp32 unheads (B,N,256) -> bf16 head-major (B,H,N,64)
__global__ __launch_bounds__(256) void pack_qk_kernel(
    const float* __restrict__ in, unsigned short* __restrict__ out)
{
  const int idx = blockIdx.x * 256 + threadIdx.x;  // < M*64
  const int m = idx >> 6, q = idx & 63;
  const int b = m / NTOK, n = m % NTOK;
  const int h = q >> 4, d = (q & 15) * 4;
  float4 v = *(const float4*)(in + (size_t)m * 256 + h * 64 + d);
  ushort4 o;
  o.x = f2bf(v.x); o.y = f2bf(v.y); o.z = f2bf(v.z); o.w = f2bf(v.w);
  *(ushort4*)(out + ((size_t)(b * NHEAD + h) * NTOK + n) * 64 + d) = o;
}

// fp32 unheads (B,N,256) -> bf16 transposed head-major (B,H,64,N)
__global__ __launch_bounds__(256) void transpose_v_kernel(
    const float* __restrict__ in, unsigned short* __restrict__ out)
{
  __shared__ float Tl[64][68];
  const int b = blockIdx.z, h = blockIdx.y;
  const int n0 = blockIdx.x * 64;
  const int t = threadIdx.x;
  {
    const int row = t >> 2;
    const int s0 = (t & 3) * 4;
#pragma unroll
    for (int i = 0; i < 4; ++i) {
      const int col = (s0 + i) * 4;
      float4 v = *(const float4*)(in + (size_t)(b * NTOK + n0 + row) * 256 + h * 64 + col);
      *(float4*)&Tl[row][col] = v;
    }
  }
  __syncthreads();
  const int d = t >> 2, qr = t & 3;
  union { unsigned short u[16]; uint4 v[2]; } pk;
#pragma unroll
  for (int j = 0; j < 16; ++j) pk.u[j] = f2bf(Tl[qr * 16 + j][d]);
  unsigned short* dst = out + ((size_t)(b * NHEAD + h) * 64 + d) * NTOK + n0 + qr * 16;
  *(uint4*)dst = pk.v[0];
  *(uint4*)(dst + 8) = pk.v[1];
}

// ---------------------------------------------------------------------------
// MFMA bf16 flash attention.
// Qh,Kh: (B,H,N,64) bf16. Vt: (B,H,64,N) bf16. O: (B,N,256) fp32 unheads.
// Block: 256 thr = 4 waves; wave w owns q rows [w*16, w*16+16) of a 64-q tile.
// K-tiles of 64. LDS pitch 72 bf16 (fragment b128 reads 2-way aliased = free).
// scale 0.125 applied to scores (covers both self 1/8 and cross (8^-.5)^2).
// ---------------------------------------------------------------------------
__global__ __launch_bounds__(256) void attn_mfma_kernel(
    const unsigned short* __restrict__ Qh, const unsigned short* __restrict__ Kh,
    const unsigned short* __restrict__ Vt, float* __restrict__ O)
{
  __shared__ unsigned short Qs[64 * 72];
  __shared__ unsigned short Ks[64 * 72];
  __shared__ unsigned short Vs[64 * 72];   // Vs[d][k]
  __shared__ unsigned short Ps[4 * 16 * 72];
  const int b = blockIdx.z, h = blockIdx.y;
  const int bh = b * NHEAD + h;
  const int n0 = blockIdx.x * 64;
  const int t = threadIdx.x, lane = t & 63, w = t >> 6;
  const int col = lane & 15, quad = lane >> 4;

  // stage Q tile (64 x 64 bf16)
  {
    const int row = t >> 2, q4 = t & 3;
    const unsigned short* src = Qh + ((size_t)bh * NTOK + n0 + row) * 64 + q4 * 16;
    uint4 a = *(const uint4*)src;
    uint4 b4 = *(const uint4*)(src + 8);
    *(uint4*)&Qs[row * 72 + q4 * 16] = a;
    *(uint4*)&Qs[row * 72 + q4 * 16 + 8] = b4;
  }
  __syncthreads();
  short8 aq[2];
#pragma unroll
  for (int kh = 0; kh < 2; ++kh)
    aq[kh] = *(const short8*)&Qs[(w * 16 + col) * 72 + quad * 8 + kh * 32];

  f32x4 o[4];
  float m_r[4], l_r[4];
#pragma unroll
  for (int i = 0; i < 4; ++i) {
    o[i] = (f32x4){0.f, 0.f, 0.f, 0.f};
    m_r[i] = -1e30f; l_r[i] = 0.f;
  }

  const int srow = t >> 2, sq4 = t & 3;
  for (int k0 = 0; k0 < NTOK; k0 += 64) {
    __syncthreads();   // previous tile's fragment reads complete
    {
      const unsigned short* ks = Kh + ((size_t)bh * NTOK + k0 + srow) * 64 + sq4 * 16;
      uint4 a = *(const uint4*)ks;
      uint4 b4 = *(const uint4*)(ks + 8);
      *(uint4*)&Ks[srow * 72 + sq4 * 16] = a;
      *(uint4*)&Ks[srow * 72 + sq4 * 16 + 8] = b4;
      const unsigned short* vs = Vt + ((size_t)bh * 64 + srow) * NTOK + k0 + sq4 * 16;
      uint4 c = *(const uint4*)vs;
      uint4 d4 = *(const uint4*)(vs + 8);
      *(uint4*)&Vs[srow * 72 + sq4 * 16] = c;
      *(uint4*)&Vs[srow * 72 + sq4 * 16 + 8] = d4;
    }
    __syncthreads();

    // S = Q @ K^T strip (16 q x 64 k)
    f32x4 sf[4];
#pragma unroll
    for (int nb = 0; nb < 4; ++nb) {
      short8 bk0 = *(const short8*)&Ks[(nb * 16 + col) * 72 + quad * 8];
      short8 bk1 = *(const short8*)&Ks[(nb * 16 + col) * 72 + quad * 8 + 32];
      f32x4 acc = (f32x4){0.f, 0.f, 0.f, 0.f};
      acc = __builtin_amdgcn_mfma_f32_16x16x32_bf16(aq[0], bk0, acc, 0, 0, 0);
      acc = __builtin_amdgcn_mfma_f32_16x16x32_bf16(aq[1], bk1, acc, 0, 0, 0);
      sf[nb] = acc;
    }

    // online softmax per q row (row = quad*4 + r)
#pragma unroll
    for (int r = 0; r < 4; ++r) {
      float mx = fmaxf(fmaxf(sf[0][r], sf[1][r]), fmaxf(sf[2][r], sf[3][r])) * 0.125f;
      mx = fmaxf(mx, __shfl_xor(mx, 1));
      mx = fmaxf(mx, __shfl_xor(mx, 2));
      mx = fmaxf(mx, __shfl_xor(mx, 4));
      mx = fmaxf(mx, __shfl_xor(mx, 8));
      const float mn = fmaxf(m_r[r], mx);
      const float alpha = __expf(m_r[r] - mn);
      m_r[r] = mn;
      float p0 = __expf(sf[0][r] * 0.125f - mn);
      float p1 = __expf(sf[1][r] * 0.125f - mn);
      float p2 = __expf(sf[2][r] * 0.125f - mn);
      float p3 = __expf(sf[3][r] * 0.125f - mn);
      float rs = p0 + p1 + p2 + p3;
      rs += __shfl_xor(rs, 1);
      rs += __shfl_xor(rs, 2);
      rs += __shfl_xor(rs, 4);
      rs += __shfl_xor(rs, 8);
      l_r[r] = l_r[r] * alpha + rs;
#pragma unroll
      for (int db = 0; db < 4; ++db) o[db][r] *= alpha;
      const int prow = (w * 16 + quad * 4 + r) * 72 + col;
      Ps[prow +  0] = f2bf(p0);
      Ps[prow + 16] = f2bf(p1);
      Ps[prow + 32] = f2bf(p2);
      Ps[prow + 48] = f2bf(p3);
    }

    // O += P @ V  (intra-wave LDS round-trip; compiler inserts lgkmcnt)
    short8 ap0 = *(const short8*)&Ps[(w * 16 + col) * 72 + quad * 8];
    short8 ap1 = *(const short8*)&Ps[(w * 16 + col) * 72 + quad * 8 + 32];
#pragma unroll
    for (int db = 0; db < 4; ++db) {
      short8 bv0 = *(const short8*)&Vs[(db * 16 + col) * 72 + quad * 8];
      short8 bv1 = *(const short8*)&Vs[(db * 16 + col) * 72 + quad * 8 + 32];
      o[db] = __builtin_amdgcn_mfma_f32_16x16x32_bf16(ap0, bv0, o[db], 0, 0, 0);
      o[db] = __builtin_amdgcn_mfma_f32_16x16x32_bf16(ap1, bv1, o[db], 0, 0, 0);
    }
  }

  // epilogue: O[q][d] = o / l
  float inv[4];
#pragma unroll
  for (int r = 0; r < 4; ++r) inv[r] = 1.f / l_r[r];
#pragma unroll
  for (int db = 0; db < 4; ++db)
#pragma unroll
    for (int r = 0; r < 4; ++r) {
      const int row = n0 + w * 16 + quad * 4 + r;
      O[(size_t)(b * NTOK + row) * 256 + h * 64 + db * 16 + col] = o[db][r] * inv[r];
    }
}

// ---------------------------------------------------------------------------
__global__ __launch_bounds__(256) void ln_gelu_kernel(
    float* __restrict__ Hm, const float* __restrict__ g,
    const float* __restrict__ be)
{
  const int wave = (blockIdx.x * 256 + threadIdx.x) >> 6;
  const int lane = threadIdx.x & 63;
  float* row = Hm + (size_t)wave * 512;
  float x[8];
  float s = 0.f;
#pragma unroll
  for (int i = 0; i < 8; ++i) { x[i] = row[lane + 64 * i]; s += x[i]; }
#pragma unroll
  for (int off = 32; off; off >>= 1) s += __shfl_xor(s, off);
  const float mean = s * (1.f / 512.f);
  float s2 = 0.f;
#pragma unroll
  for (int i = 0; i < 8; ++i) { const float d = x[i] - mean; s2 += d * d; }
#pragma unroll
  for (int off = 32; off; off >>= 1) s2 += __shfl_xor(s2, off);
  const float rstd = rsqrtf(s2 * (1.f / 512.f) + 1e-5f);
#pragma unroll
  for (int i = 0; i < 8; ++i) {
    const int c = lane + 64 * i;
    const float y = (x[i] - mean) * rstd * g[c] + be[c];
    row[c] = 0.5f * y * (1.f + erff(y * 0.70710678118654752f));
  }
}

__global__ __launch_bounds__(256) void copy_cat_kernel(
    const float* __restrict__ X, float* __restrict__ cat)
{
  const int idx = blockIdx.x * 256 + threadIdx.x;   // < M*64
  const int m = idx >> 6, c = (idx & 63) << 2;
  *(float4*)(cat + (size_t)m * 512 + c) = *(const float4*)(X + (size_t)m * 256 + c);
}

// ---------------------------------------------------------------------------
static inline void launch_gemm(const float* X, int ldx, const float* W,
                               const float* bias, const float* res, int ldr,
                               float* Y, int ldy, int Ncols, int K,
                               hipStream_t s)
{
  dim3 g(Ncols / 64, MROWS / 64);
  hipLaunchKernelGGL(gemm_kernel, g, dim3(256), 0, s,
                     X, ldx, W, bias, res, ldr, Y, ldy, K);
}

extern "C" void kernel_launch(void* const* d_in, const int* in_sizes, int n_in,
                              void* d_out, int out_size, void* d_ws, size_t ws_size,
                              hipStream_t stream) {
  const float* desc0  = (const float*)d_in[0];
  const float* desc1  = (const float*)d_in[1];
  const float* enc0   = (const float*)d_in[2];
  const float* enc1   = (const float*)d_in[3];
  const float* s_Wqkv = (const float*)d_in[4];
  const float* s_bqkv = (const float*)d_in[5];
  const float* s_Wout = (const float*)d_in[6];
  const float* s_bout = (const float*)d_in[7];
  const float* s_W1   = (const float*)d_in[8];
  const float* s_b1   = (const float*)d_in[9];
  const float* s_g    = (const float*)d_in[10];
  const float* s_be   = (const float*)d_in[11];
  const float* s_W2   = (const float*)d_in[12];
  const float* s_b2   = (const float*)d_in[13];
  const float* c_Wqk  = (const float*)d_in[14];
  const float* c_bqk  = (const float*)d_in[15];
  const float* c_Wv   = (const float*)d_in[16];
  const float* c_bv   = (const float*)d_in[17];
  const float* c_Wo   = (const float*)d_in[18];
  const float* c_bo   = (const float*)d_in[19];
  const float* c_W1   = (const float*)d_in[20];
  const float* c_b1   = (const float*)d_in[21];
  const float* c_g    = (const float*)d_in[22];
  const float* c_be   = (const float*)d_in[23];
  const float* c_W2   = (const float*)d_in[24];
  const float* c_b2   = (const float*)d_in[25];

  float* ws = (float*)d_ws;
  // arena (units of NM floats), total 12 NM = 100.7 MB:
  float* s0   = ws + 0 * NM;
  float* s1   = ws + 1 * NM;
  float* qkv  = ws + 2 * NM;           // (M,768) self; cross: qk fp32 scratch @2
  float* ctx  = ws + 2 * NM;           // alias (qkv dead after rope)
  float* m0   = ws + 3 * NM;           // cross msg 0
  float* m1   = ws + 4 * NM;           // cross msg 1
  float* vf   = ws + 5 * NM;           // fp32 V staging
  unsigned short* Vt0 = (unsigned short*)(ws + 6 * NM);        // bf16, NM elems
  unsigned short* Vt1 = Vt0 + NM;                              // region 6.5-7.0
  unsigned short* Qhb = (unsigned short*)(ws + 7 * NM);
  unsigned short* Khb = Qhb + NM;                              // region 7.5-8.0
  float* cat  = ws + 8 * NM;           // (M,512)
  float* hbuf = ws + 10 * NM;          // (M,512)

  float* out0 = (float*)d_out;
  float* out1 = out0 + NM;

  const dim3 attn_grid(NTOK / 64, NHEAD, BDIM);
  const dim3 tv_grid(NTOK / 64, NHEAD, BDIM);
  const int rope_blocks = (MROWS * 128) / 256;
  const int pack_blocks = (MROWS * 64) / 256;
  const int lng_blocks  = MROWS / 4;
  const int cpy_blocks  = (MROWS * 64) / 256;

  // ---------------- self blocks ----------------
  for (int d = 0; d < 2; ++d) {
    const float* x   = d ? desc1 : desc0;
    const float* enc = d ? enc1 : enc0;
    float* sout      = d ? s1 : s0;

    launch_gemm(x, DIM, s_Wqkv, s_bqkv, nullptr, 0, qkv, 768, 768, DIM, stream);
    hipLaunchKernelGGL(rope_repack_kernel, dim3(rope_blocks), dim3(256), 0, stream,
                       qkv, enc, Qhb, Khb, vf);
    hipLaunchKernelGGL(transpose_v_kernel, tv_grid, dim3(256), 0, stream, vf, Vt0);
    hipLaunchKernelGGL(attn_mfma_kernel, attn_grid, dim3(256), 0, stream,
                       Qhb, Khb, Vt0, ctx);
    hipLaunchKernelGGL(copy_cat_kernel, dim3(cpy_blocks), dim3(256), 0, stream, x, cat);
    launch_gemm(ctx, DIM, s_Wout, s_bout, nullptr, 0, cat + 256, 512, DIM, DIM, stream);
    launch_gemm(cat, 512, s_W1, s_b1, nullptr, 0, hbuf, 512, 512, 512, stream);
    hipLaunchKernelGGL(ln_gelu_kernel, dim3(lng_blocks), dim3(256), 0, stream,
                       hbuf, s_g, s_be);
    launch_gemm(hbuf, 512, s_W2, s_b2, x, DIM, sout, DIM, DIM, 512, stream);
  }

  // ---------------- cross block ----------------
  float* qkf = qkv;  // fp32 scratch @ region 2
  launch_gemm(s0, DIM, c_Wqk, c_bqk, nullptr, 0, qkf, DIM, DIM, DIM, stream);
  hipLaunchKernelGGL(pack_qk_kernel, dim3(pack_blocks), dim3(256), 0, stream, qkf, Qhb);
  launch_gemm(s1, DIM, c_Wqk, c_bqk, nullptr, 0, qkf, DIM, DIM, DIM, stream);
  hipLaunchKernelGGL(pack_qk_kernel, dim3(pack_blocks), dim3(256), 0, stream, qkf, Khb);
  launch_gemm(s0, DIM, c_Wv, c_bv, nullptr, 0, vf, DIM, DIM, DIM, stream);
  hipLaunchKernelGGL(transpose_v_kernel, tv_grid, dim3(256), 0, stream, vf, Vt0);
  launch_gemm(s1, DIM, c_Wv, c_bv, nullptr, 0, vf, DIM, DIM, DIM, stream);
  hipLaunchKernelGGL(transpose_v_kernel, tv_grid, dim3(256), 0, stream, vf, Vt1);
  // m0 = attn(q=qk0, k=qk1, v=v1); m1 = attn(q=qk1, k=qk0, v=v0)
  hipLaunchKernelGGL(attn_mfma_kernel, attn_grid, dim3(256), 0, stream,
                     Qhb, Khb, Vt1, m0);
  hipLaunchKernelGGL(attn_mfma_kernel, attn_grid, dim3(256), 0, stream,
                     Khb, Qhb, Vt0, m1);

  for (int d = 0; d < 2; ++d) {
    const float* sd = d ? s1 : s0;
    const float* md = d ? m1 : m0;
    float* outd     = d ? out1 : out0;
    hipLaunchKernelGGL(copy_cat_kernel, dim3(cpy_blocks), dim3(256), 0, stream, sd, cat);
    launch_gemm(md, DIM, c_Wo, c_bo, nullptr, 0, cat + 256, 512, DIM, DIM, stream);
    launch_gemm(cat, 512, c_W1, c_b1, nullptr, 0, hbuf, 512, 512, 512, stream);
    hipLaunchKernelGGL(ln_gelu_kernel, dim3(lng_blocks), dim3(256), 0, stream,
                       hbuf, c_g, c_be);
    launch_gemm(hbuf, 512, c_W2, c_b2, sd, DIM, outd, DIM, DIM, 512, stream);
  }
}

// Round 3
// 861.516 us; speedup vs baseline: 6.6684x; 1.5219x over previous
//
#include <hip/hip_runtime.h>
#include <cstddef>

#define NTOK 2048
#define BDIM 4
#define DIM 256
#define NHEAD 4
#define HDIM 64
#define MROWS (BDIM * NTOK)            // 8192
#define NMu ((size_t)MROWS * DIM)      // 2,097,152 elems (bf16 unit = 4 MB)

typedef unsigned short u16;
typedef __attribute__((ext_vector_type(8))) short short8;
typedef __attribute__((ext_vector_type(4))) float f32x4;

__device__ __forceinline__ u16 f2bf(float x) {
  union { float f; unsigned u; } c; c.f = x;
  unsigned r = c.u + 0x7FFFu + ((c.u >> 16) & 1u);
  return (u16)(r >> 16);
}
__device__ __forceinline__ float bf2f(u16 u) {
  union { unsigned u; float f; } c; c.u = ((unsigned)u) << 16;
  return c.f;
}

__device__ __forceinline__ void glds16(const void* g, void* l) {
  __builtin_amdgcn_global_load_lds(
      (const __attribute__((address_space(1))) unsigned int*)g,
      (__attribute__((address_space(3))) unsigned int*)l, 16, 0, 0);
}

// ---------------------------------------------------------------------------
// bf16 MFMA GEMM (m97 structure): Y = A @ W^T + bias (+res)
// A: (8192, K) bf16 row-major (split: rows use A for k<kSplit, A2 after).
// W: (N, K) bf16 row-major. 128x128 tile, BK=32, 256 thr, 2x2 waves,
// 4x4 16x16x32 accumulators per wave. Epilogue: optional fp32/bf16 residual,
// optional fp32 and/or bf16 output.
// ---------------------------------------------------------------------------
__global__ __launch_bounds__(256) void gemm_bf16_kernel(
    const u16* __restrict__ A, int lda,
    const u16* __restrict__ A2, int lda2, int kSplit,
    const u16* __restrict__ W,
    const float* __restrict__ bias,
    const float* __restrict__ resf, int ldrf,
    const u16* __restrict__ resb, int ldrb,
    float* __restrict__ Yf, int ldyf,
    u16* __restrict__ Yb, int ldyb,
    int K)
{
  __shared__ u16 As[128 * 32];
  __shared__ u16 Bs[128 * 32];
  const int t = threadIdx.x;
  const int m0 = blockIdx.y * 128, n0 = blockIdx.x * 128;
  const int r4 = t >> 2, c8 = (t & 3) * 8;
  const int lane = t & 63, w = t >> 6;
  const int cl = lane & 15, quad = lane >> 4;
  const int wm = (w >> 1) * 64, wn = (w & 1) * 64;

  f32x4 acc[4][4];
#pragma unroll
  for (int i = 0; i < 4; ++i)
#pragma unroll
    for (int j = 0; j < 4; ++j) acc[i][j] = (f32x4){0.f, 0.f, 0.f, 0.f};

  for (int k0 = 0; k0 < K; k0 += 32) {
    const u16* Ab; int la; int kk;
    if (k0 < kSplit) { Ab = A; la = lda; kk = k0; }
    else             { Ab = A2; la = lda2; kk = k0 - kSplit; }
    const u16* ag = Ab + (size_t)(m0 + r4) * la + kk + c8;
    const u16* bg = W + (size_t)(n0 + r4) * K + k0 + c8;
    __syncthreads();                       // prev compute done with LDS
    glds16(ag, &As[t * 8]);
    glds16(ag + (size_t)64 * la, &As[2048 + t * 8]);
    glds16(bg, &Bs[t * 8]);
    glds16(bg + (size_t)64 * K, &Bs[2048 + t * 8]);
    __syncthreads();                       // vmcnt(0) drain + barrier

    short8 af[4], bfr[4];
#pragma unroll
    for (int i = 0; i < 4; ++i)
      af[i] = *(const short8*)&As[(wm + i * 16 + cl) * 32 + quad * 8];
#pragma unroll
    for (int i = 0; i < 4; ++i)
      bfr[i] = *(const short8*)&Bs[(wn + i * 16 + cl) * 32 + quad * 8];
#pragma unroll
    for (int mt = 0; mt < 4; ++mt)
#pragma unroll
      for (int nt = 0; nt < 4; ++nt)
        acc[mt][nt] = __builtin_amdgcn_mfma_f32_16x16x32_bf16(
            af[mt], bfr[nt], acc[mt][nt], 0, 0, 0);
  }

#pragma unroll
  for (int mt = 0; mt < 4; ++mt)
#pragma unroll
    for (int nt = 0; nt < 4; ++nt) {
      const int colg = n0 + wn + nt * 16 + cl;
      const float bs = bias[colg];
#pragma unroll
      for (int r = 0; r < 4; ++r) {
        const int rowg = m0 + wm + mt * 16 + quad * 4 + r;
        float v = acc[mt][nt][r] + bs;
        if (resf) v += resf[(size_t)rowg * ldrf + colg];
        if (resb) v += bf2f(resb[(size_t)rowg * ldrb + colg]);
        if (Yf) Yf[(size_t)rowg * ldyf + colg] = v;
        if (Yb) Yb[(size_t)rowg * ldyb + colg] = f2bf(v);
      }
    }
}

// ---------------------------------------------------------------------------
// RoPE: qkvb bf16 (M,768) col = h*192 + hd*3 + {q,k,v} -> Qu,Ku (rope) and Vu,
// all bf16 unheads (M,256) col = h*64+hd.
// ---------------------------------------------------------------------------
__global__ __launch_bounds__(256) void rope_repack_kernel(
    const u16* __restrict__ qkv, const float* __restrict__ enc,
    u16* __restrict__ Q, u16* __restrict__ K, u16* __restrict__ V)
{
  const int idx = blockIdx.x * blockDim.x + threadIdx.x;  // < M*4*32
  const int i = idx & 31;
  const int h = (idx >> 5) & 3;
  const int m = idx >> 7;
  const u16* src = qkv + (size_t)m * 768 + h * 192 + i * 6;
  const unsigned a0 = *(const unsigned*)(src);
  const unsigned a1 = *(const unsigned*)(src + 2);
  const unsigned a2 = *(const unsigned*)(src + 4);
  const float q0 = bf2f((u16)a0), k0 = bf2f((u16)(a0 >> 16));
  const float v0 = bf2f((u16)a1), q1 = bf2f((u16)(a1 >> 16));
  const float k1 = bf2f((u16)a2), v1 = bf2f((u16)(a2 >> 16));
  const float c = enc[(size_t)m * 64 + 2 * i];
  const float s = enc[(size_t)BDIM * NTOK * 64 + (size_t)m * 64 + 2 * i];
  const size_t o = (size_t)m * 256 + h * 64 + 2 * i;
  *(unsigned*)(Q + o) = (unsigned)f2bf(q0 * c - q1 * s) | ((unsigned)f2bf(q1 * c + q0 * s) << 16);
  *(unsigned*)(K + o) = (unsigned)f2bf(k0 * c - k1 * s) | ((unsigned)f2bf(k1 * c + k0 * s) << 16);
  *(unsigned*)(V + o) = a1 & 0xFFFFu ? ((unsigned)f2bf(v0) | ((unsigned)f2bf(v1) << 16))
                                     : ((unsigned)f2bf(v0) | ((unsigned)f2bf(v1) << 16));
}

// bf16 unheads (M,256) -> bf16 transposed head-major (B,H,64,N)
__global__ __launch_bounds__(256) void transpose_v_kernel(
    const u16* __restrict__ in, u16* __restrict__ out)
{
  __shared__ u16 Tl[64][72];
  const int b = blockIdx.z, h = blockIdx.y;
  const int n0 = blockIdx.x * 64;
  const int t = threadIdx.x;
  {
    const int row = t >> 2, c16 = (t & 3) * 16;
    const u16* src = in + (size_t)(b * NTOK + n0 + row) * 256 + h * 64 + c16;
    *(uint4*)&Tl[row][c16] = *(const uint4*)src;
    *(uint4*)&Tl[row][c16 + 8] = *(const uint4*)(src + 8);
  }
  __syncthreads();
  const int d = t >> 2, qr = t & 3;
  union { u16 u[16]; uint4 v[2]; } pk;
#pragma unroll
  for (int j = 0; j < 16; ++j) pk.u[j] = Tl[qr * 16 + j][d];
  u16* dst = out + ((size_t)((b * NHEAD + h) * 64 + d)) * NTOK + n0 + qr * 16;
  *(uint4*)dst = pk.v[0];
  *(uint4*)(dst + 8) = pk.v[1];
}

// ---------------------------------------------------------------------------
// MFMA bf16 flash attention. Q,K: bf16 unheads (M,256) col=h*64+d.
// Vt: (B,H,64,N) bf16. O: bf16 unheads (M,256). scale 0.125.
// ---------------------------------------------------------------------------
__global__ __launch_bounds__(256) void attn_mfma_kernel(
    const u16* __restrict__ Qu, const u16* __restrict__ Ku,
    const u16* __restrict__ Vt, u16* __restrict__ O)
{
  __shared__ u16 Qs[64 * 72];
  __shared__ u16 Ks[64 * 72];
  __shared__ u16 Vs[64 * 72];   // Vs[d][k]
  __shared__ u16 Ps[4 * 16 * 72];
  const int b = blockIdx.z, h = blockIdx.y;
  const int bh = b * NHEAD + h;
  const int n0 = blockIdx.x * 64;
  const int t = threadIdx.x, lane = t & 63, w = t >> 6;
  const int col = lane & 15, quad = lane >> 4;

  {
    const int row = t >> 2, q4 = (t & 3) * 16;
    const u16* src = Qu + (size_t)(b * NTOK + n0 + row) * 256 + h * 64 + q4;
    *(uint4*)&Qs[row * 72 + q4] = *(const uint4*)src;
    *(uint4*)&Qs[row * 72 + q4 + 8] = *(const uint4*)(src + 8);
  }
  __syncthreads();
  short8 aq[2];
#pragma unroll
  for (int kh = 0; kh < 2; ++kh)
    aq[kh] = *(const short8*)&Qs[(w * 16 + col) * 72 + quad * 8 + kh * 32];

  f32x4 o[4];
  float m_r[4], l_r[4];
#pragma unroll
  for (int i = 0; i < 4; ++i) {
    o[i] = (f32x4){0.f, 0.f, 0.f, 0.f};
    m_r[i] = -1e30f; l_r[i] = 0.f;
  }

  const int srow = t >> 2, sq4 = (t & 3) * 16;
  for (int k0 = 0; k0 < NTOK; k0 += 64) {
    __syncthreads();
    {
      const u16* ks = Ku + (size_t)(b * NTOK + k0 + srow) * 256 + h * 64 + sq4;
      *(uint4*)&Ks[srow * 72 + sq4] = *(const uint4*)ks;
      *(uint4*)&Ks[srow * 72 + sq4 + 8] = *(const uint4*)(ks + 8);
      const u16* vs = Vt + ((size_t)bh * 64 + srow) * NTOK + k0 + sq4;
      *(uint4*)&Vs[srow * 72 + sq4] = *(const uint4*)vs;
      *(uint4*)&Vs[srow * 72 + sq4 + 8] = *(const uint4*)(vs + 8);
    }
    __syncthreads();

    f32x4 sf[4];
#pragma unroll
    for (int nb = 0; nb < 4; ++nb) {
      short8 bk0 = *(const short8*)&Ks[(nb * 16 + col) * 72 + quad * 8];
      short8 bk1 = *(const short8*)&Ks[(nb * 16 + col) * 72 + quad * 8 + 32];
      f32x4 acc = (f32x4){0.f, 0.f, 0.f, 0.f};
      acc = __builtin_amdgcn_mfma_f32_16x16x32_bf16(aq[0], bk0, acc, 0, 0, 0);
      acc = __builtin_amdgcn_mfma_f32_16x16x32_bf16(aq[1], bk1, acc, 0, 0, 0);
      sf[nb] = acc;
    }

#pragma unroll
    for (int r = 0; r < 4; ++r) {
      float mx = fmaxf(fmaxf(sf[0][r], sf[1][r]), fmaxf(sf[2][r], sf[3][r])) * 0.125f;
      mx = fmaxf(mx, __shfl_xor(mx, 1));
      mx = fmaxf(mx, __shfl_xor(mx, 2));
      mx = fmaxf(mx, __shfl_xor(mx, 4));
      mx = fmaxf(mx, __shfl_xor(mx, 8));
      const float mn = fmaxf(m_r[r], mx);
      const float alpha = __expf(m_r[r] - mn);
      m_r[r] = mn;
      float p0 = __expf(sf[0][r] * 0.125f - mn);
      float p1 = __expf(sf[1][r] * 0.125f - mn);
      float p2 = __expf(sf[2][r] * 0.125f - mn);
      float p3 = __expf(sf[3][r] * 0.125f - mn);
      float rs = p0 + p1 + p2 + p3;
      rs += __shfl_xor(rs, 1);
      rs += __shfl_xor(rs, 2);
      rs += __shfl_xor(rs, 4);
      rs += __shfl_xor(rs, 8);
      l_r[r] = l_r[r] * alpha + rs;
#pragma unroll
      for (int db = 0; db < 4; ++db) o[db][r] *= alpha;
      const int prow = (w * 16 + quad * 4 + r) * 72 + col;
      Ps[prow +  0] = f2bf(p0);
      Ps[prow + 16] = f2bf(p1);
      Ps[prow + 32] = f2bf(p2);
      Ps[prow + 48] = f2bf(p3);
    }

    short8 ap0 = *(const short8*)&Ps[(w * 16 + col) * 72 + quad * 8];
    short8 ap1 = *(const short8*)&Ps[(w * 16 + col) * 72 + quad * 8 + 32];
#pragma unroll
    for (int db = 0; db < 4; ++db) {
      short8 bv0 = *(const short8*)&Vs[(db * 16 + col) * 72 + quad * 8];
      short8 bv1 = *(const short8*)&Vs[(db * 16 + col) * 72 + quad * 8 + 32];
      o[db] = __builtin_amdgcn_mfma_f32_16x16x32_bf16(ap0, bv0, o[db], 0, 0, 0);
      o[db] = __builtin_amdgcn_mfma_f32_16x16x32_bf16(ap1, bv1, o[db], 0, 0, 0);
    }
  }

  float inv[4];
#pragma unroll
  for (int r = 0; r < 4; ++r) inv[r] = 1.f / l_r[r];
#pragma unroll
  for (int db = 0; db < 4; ++db)
#pragma unroll
    for (int r = 0; r < 4; ++r) {
      const int row = n0 + w * 16 + quad * 4 + r;
      O[(size_t)(b * NTOK + row) * 256 + h * 64 + db * 16 + col] = f2bf(o[db][r] * inv[r]);
    }
}

// ---------------------------------------------------------------------------
// LayerNorm + exact GELU: hbuf fp32 (M,512) -> hb2 bf16 (M,512)
// ---------------------------------------------------------------------------
__global__ __launch_bounds__(256) void ln_gelu_kernel(
    const float* __restrict__ Hm, const float* __restrict__ g,
    const float* __restrict__ be, u16* __restrict__ out)
{
  const int wave = (blockIdx.x * 256 + threadIdx.x) >> 6;
  const int lane = threadIdx.x & 63;
  const float* row = Hm + (size_t)wave * 512;
  u16* orow = out + (size_t)wave * 512;
  float x[8];
  float s = 0.f;
#pragma unroll
  for (int i = 0; i < 8; ++i) { x[i] = row[lane + 64 * i]; s += x[i]; }
#pragma unroll
  for (int off = 32; off; off >>= 1) s += __shfl_xor(s, off);
  const float mean = s * (1.f / 512.f);
  float s2 = 0.f;
#pragma unroll
  for (int i = 0; i < 8; ++i) { const float d = x[i] - mean; s2 += d * d; }
#pragma unroll
  for (int off = 32; off; off >>= 1) s2 += __shfl_xor(s2, off);
  const float rstd = rsqrtf(s2 * (1.f / 512.f) + 1e-5f);
#pragma unroll
  for (int i = 0; i < 8; ++i) {
    const int c = lane + 64 * i;
    const float y = (x[i] - mean) * rstd * g[c] + be[c];
    orow[c] = f2bf(0.5f * y * (1.f + erff(y * 0.70710678118654752f)));
  }
}

// fp32 (M,256) -> bf16
__global__ __launch_bounds__(256) void pack_desc_kernel(
    const float* __restrict__ in, u16* __restrict__ out)
{
  const size_t i4 = ((size_t)blockIdx.x * 256 + threadIdx.x) * 4;
  float4 v = *(const float4*)(in + i4);
  ushort4 o;
  o.x = f2bf(v.x); o.y = f2bf(v.y); o.z = f2bf(v.z); o.w = f2bf(v.w);
  *(ushort4*)(out + i4) = o;
}

// all 9 weight matrices fp32 -> bf16, concatenated
__global__ __launch_bounds__(256) void pack_weights_kernel(
    const float* w0, const float* w1, const float* w2, const float* w3,
    const float* w4, const float* w5, const float* w6, const float* w7,
    const float* w8, u16* __restrict__ out)
{
  const int idx4 = (blockIdx.x * 256 + threadIdx.x) * 4;
  const float* src; int off;
  if      (idx4 <  196608) { src = w0; off = idx4; }
  else if (idx4 <  262144) { src = w1; off = idx4 - 196608; }
  else if (idx4 <  524288) { src = w2; off = idx4 - 262144; }
  else if (idx4 <  655360) { src = w3; off = idx4 - 524288; }
  else if (idx4 <  720896) { src = w4; off = idx4 - 655360; }
  else if (idx4 <  786432) { src = w5; off = idx4 - 720896; }
  else if (idx4 <  851968) { src = w6; off = idx4 - 786432; }
  else if (idx4 < 1114112) { src = w7; off = idx4 - 851968; }
  else                     { src = w8; off = idx4 - 1114112; }
  float4 v = *(const float4*)(src + off);
  ushort4 o;
  o.x = f2bf(v.x); o.y = f2bf(v.y); o.z = f2bf(v.z); o.w = f2bf(v.w);
  *(ushort4*)(out + idx4) = o;
}

// ---------------------------------------------------------------------------
static inline void launch_gemm(const u16* A, int lda, const u16* A2, int lda2,
                               int kSplit, const u16* W, const float* bias,
                               const float* resf, int ldrf,
                               const u16* resb, int ldrb,
                               float* Yf, int ldyf, u16* Yb, int ldyb,
                               int N, int K, hipStream_t s)
{
  dim3 g(N / 128, MROWS / 128);
  hipLaunchKernelGGL(gemm_bf16_kernel, g, dim3(256), 0, s,
                     A, lda, A2, lda2, kSplit, W, bias,
                     resf, ldrf, resb, ldrb, Yf, ldyf, Yb, ldyb, K);
}

extern "C" void kernel_launch(void* const* d_in, const int* in_sizes, int n_in,
                              void* d_out, int out_size, void* d_ws, size_t ws_size,
                              hipStream_t stream) {
  const float* desc0  = (const float*)d_in[0];
  const float* desc1  = (const float*)d_in[1];
  const float* enc0   = (const float*)d_in[2];
  const float* enc1   = (const float*)d_in[3];
  const float* s_Wqkv = (const float*)d_in[4];
  const float* s_bqkv = (const float*)d_in[5];
  const float* s_Wout = (const float*)d_in[6];
  const float* s_bout = (const float*)d_in[7];
  const float* s_W1   = (const float*)d_in[8];
  const float* s_b1   = (const float*)d_in[9];
  const float* s_g    = (const float*)d_in[10];
  const float* s_be   = (const float*)d_in[11];
  const float* s_W2   = (const float*)d_in[12];
  const float* s_b2   = (const float*)d_in[13];
  const float* c_Wqk  = (const float*)d_in[14];
  const float* c_bqk  = (const float*)d_in[15];
  const float* c_Wv   = (const float*)d_in[16];
  const float* c_bv   = (const float*)d_in[17];
  const float* c_Wo   = (const float*)d_in[18];
  const float* c_bo   = (const float*)d_in[19];
  const float* c_W1   = (const float*)d_in[20];
  const float* c_b1   = (const float*)d_in[21];
  const float* c_g    = (const float*)d_in[22];
  const float* c_be   = (const float*)d_in[23];
  const float* c_W2   = (const float*)d_in[24];
  const float* c_b2   = (const float*)d_in[25];

  u16* U = (u16*)d_ws;
  // arena in units of NMu bf16 elems (4 MB):
  u16* descb0 = U + 0 * NMu;
  u16* descb1 = U + 1 * NMu;
  u16* qkvb   = U + 2 * NMu;           // 3 units (self); cross aliases below
  u16* ctxb   = U + 2 * NMu;           // alias (qkv dead after rope)
  u16* v1b    = U + 2 * NMu;           // cross alias
  u16* m0b    = U + 3 * NMu;
  u16* m1b    = U + 4 * NMu;
  u16* Qu     = U + 5 * NMu;           // cross: qk0b
  u16* Ku     = U + 6 * NMu;           // cross: qk1b
  u16* Vu     = U + 7 * NMu;           // cross: v0b
  u16* Vt0    = U + 8 * NMu;
  u16* Vt1    = U + 9 * NMu;
  u16* msgb   = U + 10 * NMu;
  u16* hb2    = U + 11 * NMu;          // 2 units (M,512)
  u16* s0b    = U + 13 * NMu;
  u16* s1b    = U + 14 * NMu;
  float* hbuf = (float*)(U + 15 * NMu);  // 4 units (M,512 fp32)
  float* s0f  = (float*)(U + 19 * NMu);  // 2 units
  float* s1f  = (float*)(U + 21 * NMu);  // 2 units
  u16* wb     = U + 23 * NMu;            // 1,245,184 bf16 weights

  u16* Wqkvb = wb;
  u16* Woutb = wb + 196608;
  u16* W1b   = wb + 262144;
  u16* W2b   = wb + 524288;
  u16* cWqkb = wb + 655360;
  u16* cWvb  = wb + 720896;
  u16* cWob  = wb + 786432;
  u16* cW1b  = wb + 851968;
  u16* cW2b  = wb + 1114112;

  float* out0 = (float*)d_out;
  float* out1 = out0 + NMu;

  const dim3 attn_grid(NTOK / 64, NHEAD, BDIM);
  const int rope_blocks = (MROWS * 128) / 256;
  const int lng_blocks  = MROWS / 4;
  const int desc_blocks = (int)(NMu / 4 / 256);

  hipLaunchKernelGGL(pack_weights_kernel, dim3(1216), dim3(256), 0, stream,
                     s_Wqkv, s_Wout, s_W1, s_W2, c_Wqk, c_Wv, c_Wo, c_W1, c_W2, wb);
  hipLaunchKernelGGL(pack_desc_kernel, dim3(desc_blocks), dim3(256), 0, stream, desc0, descb0);
  hipLaunchKernelGGL(pack_desc_kernel, dim3(desc_blocks), dim3(256), 0, stream, desc1, descb1);

  // ---------------- self blocks ----------------
  for (int d = 0; d < 2; ++d) {
    const u16* xb    = d ? descb1 : descb0;
    const float* xf  = d ? desc1 : desc0;
    const float* enc = d ? enc1 : enc0;
    u16* soutb       = d ? s1b : s0b;
    float* soutf     = d ? s1f : s0f;

    launch_gemm(xb, 256, nullptr, 0, 1 << 30, Wqkvb, s_bqkv,
                nullptr, 0, nullptr, 0, nullptr, 0, qkvb, 768, 768, 256, stream);
    hipLaunchKernelGGL(rope_repack_kernel, dim3(rope_blocks), dim3(256), 0, stream,
                       qkvb, enc, Qu, Ku, Vu);
    hipLaunchKernelGGL(transpose_v_kernel, attn_grid, dim3(256), 0, stream, Vu, Vt0);
    hipLaunchKernelGGL(attn_mfma_kernel, attn_grid, dim3(256), 0, stream,
                       Qu, Ku, Vt0, ctxb);
    launch_gemm(ctxb, 256, nullptr, 0, 1 << 30, Woutb, s_bout,
                nullptr, 0, nullptr, 0, nullptr, 0, msgb, 256, 256, 256, stream);
    launch_gemm(xb, 256, msgb, 256, 256, W1b, s_b1,
                nullptr, 0, nullptr, 0, hbuf, 512, nullptr, 0, 512, 512, stream);
    hipLaunchKernelGGL(ln_gelu_kernel, dim3(lng_blocks), dim3(256), 0, stream,
                       hbuf, s_g, s_be, hb2);
    launch_gemm(hb2, 512, nullptr, 0, 1 << 30, W2b, s_b2,
                xf, 256, nullptr, 0, soutf, 256, soutb, 256, 256, 512, stream);
  }

  // ---------------- cross block ----------------
  u16* qk0b = Qu;
  u16* qk1b = Ku;
  u16* v0b  = Vu;
  launch_gemm(s0b, 256, nullptr, 0, 1 << 30, cWqkb, c_bqk,
              nullptr, 0, nullptr, 0, nullptr, 0, qk0b, 256, 256, 256, stream);
  launch_gemm(s1b, 256, nullptr, 0, 1 << 30, cWqkb, c_bqk,
              nullptr, 0, nullptr, 0, nullptr, 0, qk1b, 256, 256, 256, stream);
  launch_gemm(s0b, 256, nullptr, 0, 1 << 30, cWvb, c_bv,
              nullptr, 0, nullptr, 0, nullptr, 0, v0b, 256, 256, 256, stream);
  launch_gemm(s1b, 256, nullptr, 0, 1 << 30, cWvb, c_bv,
              nullptr, 0, nullptr, 0, nullptr, 0, v1b, 256, 256, 256, stream);
  hipLaunchKernelGGL(transpose_v_kernel, attn_grid, dim3(256), 0, stream, v0b, Vt0);
  hipLaunchKernelGGL(transpose_v_kernel, attn_grid, dim3(256), 0, stream, v1b, Vt1);
  hipLaunchKernelGGL(attn_mfma_kernel, attn_grid, dim3(256), 0, stream,
                     qk0b, qk1b, Vt1, m0b);
  hipLaunchKernelGGL(attn_mfma_kernel, attn_grid, dim3(256), 0, stream,
                     qk1b, qk0b, Vt0, m1b);

  for (int d = 0; d < 2; ++d) {
    const u16* sdb   = d ? s1b : s0b;
    const float* sdf = d ? s1f : s0f;
    const u16* mdb   = d ? m1b : m0b;
    float* outd      = d ? out1 : out0;
    launch_gemm(mdb, 256, nullptr, 0, 1 << 30, cWob, c_bo,
                nullptr, 0, nullptr, 0, nullptr, 0, msgb, 256, 256, 256, stream);
    launch_gemm(sdb, 256, msgb, 256, 256, cW1b, c_b1,
                nullptr, 0, nullptr, 0, hbuf, 512, nullptr, 0, 512, 512, stream);
    hipLaunchKernelGGL(ln_gelu_kernel, dim3(lng_blocks), dim3(256), 0, stream,
                       hbuf, c_g, c_be, hb2);
    launch_gemm(hb2, 512, nullptr, 0, 1 << 30, cW2b, c_b2,
                sdf, 256, nullptr, 0, outd, 256, nullptr, 0, 256, 512, stream);
  }
}

// Round 4
// 496.776 us; speedup vs baseline: 11.5644x; 1.7342x over previous
//
#include <hip/hip_runtime.h>
#include <cstddef>

#define NTOK 2048
#define BDIM 4
#define DIM 256
#define NHEAD 4
#define MROWS 8192
#define M2 16384                        // both descriptors batched
#define NMu ((size_t)MROWS * DIM)       // 2,097,152 elems (bf16 unit = 4 MB)

typedef unsigned short u16;
typedef __attribute__((ext_vector_type(8))) short short8;
typedef __attribute__((ext_vector_type(4))) float f32x4;

__device__ __forceinline__ u16 f2bf(float x) {
  union { float f; unsigned u; } c; c.f = x;
  unsigned r = c.u + 0x7FFFu + ((c.u >> 16) & 1u);
  return (u16)(r >> 16);
}
__device__ __forceinline__ float bf2f(u16 u) {
  union { unsigned u; float f; } c; c.u = ((unsigned)u) << 16;
  return c.f;
}

__device__ __forceinline__ void glds16(const void* g, void* l) {
  __builtin_amdgcn_global_load_lds(
      (const __attribute__((address_space(1))) unsigned int*)g,
      (__attribute__((address_space(3))) unsigned int*)l, 16, 0, 0);
}

// ---------------------------------------------------------------------------
// bf16 MFMA GEMM: Y = (A @ W^T + bias) * oscale (+res). 16384 rows.
// ---------------------------------------------------------------------------
__global__ __launch_bounds__(256) void gemm_bf16_kernel(
    const u16* __restrict__ A, int lda,
    const u16* __restrict__ A2, int lda2, int kSplit,
    const u16* __restrict__ W,
    const float* __restrict__ bias, float oscale,
    const u16* __restrict__ resb, int ldrb,
    float* __restrict__ Yf, int ldyf,
    u16* __restrict__ Yb, int ldyb,
    int K)
{
  __shared__ u16 As[128 * 32];
  __shared__ u16 Bs[128 * 32];
  const int t = threadIdx.x;
  const int m0 = blockIdx.y * 128, n0 = blockIdx.x * 128;
  const int r4 = t >> 2, c8 = (t & 3) * 8;
  const int lane = t & 63, w = t >> 6;
  const int cl = lane & 15, quad = lane >> 4;
  const int wm = (w >> 1) * 64, wn = (w & 1) * 64;

  f32x4 acc[4][4];
#pragma unroll
  for (int i = 0; i < 4; ++i)
#pragma unroll
    for (int j = 0; j < 4; ++j) acc[i][j] = (f32x4){0.f, 0.f, 0.f, 0.f};

  for (int k0 = 0; k0 < K; k0 += 32) {
    const u16* Ab; int la; int kk;
    if (k0 < kSplit) { Ab = A; la = lda; kk = k0; }
    else             { Ab = A2; la = lda2; kk = k0 - kSplit; }
    const u16* ag = Ab + (size_t)(m0 + r4) * la + kk + c8;
    const u16* bg = W + (size_t)(n0 + r4) * K + k0 + c8;
    __syncthreads();
    glds16(ag, &As[t * 8]);
    glds16(ag + (size_t)64 * la, &As[2048 + t * 8]);
    glds16(bg, &Bs[t * 8]);
    glds16(bg + (size_t)64 * K, &Bs[2048 + t * 8]);
    __syncthreads();

    short8 af[4], bfr[4];
#pragma unroll
    for (int i = 0; i < 4; ++i)
      af[i] = *(const short8*)&As[(wm + i * 16 + cl) * 32 + quad * 8];
#pragma unroll
    for (int i = 0; i < 4; ++i)
      bfr[i] = *(const short8*)&Bs[(wn + i * 16 + cl) * 32 + quad * 8];
#pragma unroll
    for (int mt = 0; mt < 4; ++mt)
#pragma unroll
      for (int nt = 0; nt < 4; ++nt)
        acc[mt][nt] = __builtin_amdgcn_mfma_f32_16x16x32_bf16(
            af[mt], bfr[nt], acc[mt][nt], 0, 0, 0);
  }

#pragma unroll
  for (int mt = 0; mt < 4; ++mt)
#pragma unroll
    for (int nt = 0; nt < 4; ++nt) {
      const int colg = n0 + wn + nt * 16 + cl;
      const float bs = bias[colg];
#pragma unroll
      for (int r = 0; r < 4; ++r) {
        const int rowg = m0 + wm + mt * 16 + quad * 4 + r;
        float v = (acc[mt][nt][r] + bs) * oscale;
        if (resb) v += bf2f(resb[(size_t)rowg * ldrb + colg]);
        if (Yf) Yf[(size_t)rowg * ldyf + colg] = v;
        if (Yb) Yb[(size_t)rowg * ldyb + colg] = f2bf(v);
      }
    }
}

// ---------------------------------------------------------------------------
// RoPE batched over both descriptors. qkv (M2,768) -> Qu (scaled 0.125), Ku,
// Vu, all bf16 unheads (M2,256).
// ---------------------------------------------------------------------------
__global__ __launch_bounds__(256) void rope_repack_kernel(
    const u16* __restrict__ qkv, const float* __restrict__ enc0,
    const float* __restrict__ enc1,
    u16* __restrict__ Q, u16* __restrict__ K, u16* __restrict__ V)
{
  const int idx = blockIdx.x * blockDim.x + threadIdx.x;  // < M2*4*32
  const int i = idx & 31;
  const int h = (idx >> 5) & 3;
  const int m = idx >> 7;                 // 0..16383
  const int half = m >> 13;
  const int lm = m & (MROWS - 1);
  const float* enc = half ? enc1 : enc0;
  const u16* src = qkv + (size_t)m * 768 + h * 192 + i * 6;
  const unsigned a0 = *(const unsigned*)(src);
  const unsigned a1 = *(const unsigned*)(src + 2);
  const unsigned a2 = *(const unsigned*)(src + 4);
  const float q0 = bf2f((u16)a0), k0 = bf2f((u16)(a0 >> 16));
  const float v0 = bf2f((u16)a1), q1 = bf2f((u16)(a1 >> 16));
  const float k1 = bf2f((u16)a2), v1 = bf2f((u16)(a2 >> 16));
  const float c = enc[(size_t)lm * 64 + 2 * i];
  const float s = enc[(size_t)MROWS * 64 + (size_t)lm * 64 + 2 * i];
  const size_t o = (size_t)m * 256 + h * 64 + 2 * i;
  // fold attention scale 1/8 into Q
  *(unsigned*)(Q + o) = (unsigned)f2bf((q0 * c - q1 * s) * 0.125f) |
                        ((unsigned)f2bf((q1 * c + q0 * s) * 0.125f) << 16);
  *(unsigned*)(K + o) = (unsigned)f2bf(k0 * c - k1 * s) |
                        ((unsigned)f2bf(k1 * c + k0 * s) << 16);
  *(unsigned*)(V + o) = (a1 & 0xFFFF0000u) | (a1 & 0xFFFFu);
}

// bf16 unheads (M2,256) -> bf16 transposed head-major (8,H,64,2048)
__global__ __launch_bounds__(256) void transpose_v_kernel(
    const u16* __restrict__ in, u16* __restrict__ out)
{
  __shared__ u16 Tl[64][72];
  const int bz = blockIdx.z, h = blockIdx.y;
  const int n0 = blockIdx.x * 64;
  const int t = threadIdx.x;
  {
    const int row = t >> 2, c16 = (t & 3) * 16;
    const u16* src = in + (size_t)(bz * NTOK + n0 + row) * 256 + h * 64 + c16;
    *(uint4*)&Tl[row][c16] = *(const uint4*)src;
    *(uint4*)&Tl[row][c16 + 8] = *(const uint4*)(src + 8);
  }
  __syncthreads();
  const int d = t >> 2, qr = t & 3;
  union { u16 u[16]; uint4 v[2]; } pk;
#pragma unroll
  for (int j = 0; j < 16; ++j) pk.u[j] = Tl[qr * 16 + j][d];
  u16* dst = out + ((size_t)((bz * NHEAD + h) * 64 + d)) * NTOK + n0 + qr * 16;
  *(uint4*)dst = pk.v[0];
  *(uint4*)(dst + 8) = pk.v[1];
}

// ---------------------------------------------------------------------------
// MFMA flash attention, S^T formulation, K-split partials.
// grid: (32 q-tiles, 32 = half*16+b*4+h, 2 k-split). Block 256 = 4 waves,
// wave owns 16 q (one per lane&15, replicated over quads).
// S^T = K·Q^T via mfma(A=K,B=Q): D[key=quad*4+r][q=lane&15] -> softmax per
// lane is 15 fmax + 2 shfl. P^T written as B-frag rows via ds_write_b64,
// O^T = V^T·P^T accumulated; partials (o,m,l) stored for combine kernel.
// ---------------------------------------------------------------------------
__global__ __launch_bounds__(256, 4) void attn2_kernel(
    const u16* __restrict__ Qb, const u16* __restrict__ Kb,
    const u16* __restrict__ Vtb,
    u16* __restrict__ Po, float* __restrict__ Pm, float* __restrict__ Pl,
    int cross)
{
  __shared__ u16 Ks[64 * 72];
  __shared__ u16 Vs[64 * 72];
  __shared__ u16 QPs[64 * 72];   // Q tile, then per-wave P^T region (rows w*16..)
  const int y = blockIdx.y, z = blockIdx.z;
  const int h2 = y >> 4, b = (y >> 2) & 3, h = y & 3;
  const int kh = cross ? (1 - h2) : h2;
  const int qrowbase = (h2 * 4 + b) * NTOK;
  const int krowbase = (kh * 4 + b) * NTOK + z * 1024;
  const int vz = kh * 4 + b;
  const int n0 = blockIdx.x * 64;
  const int t = threadIdx.x, lane = t & 63, w = t >> 6;
  const int cl = lane & 15, quad = lane >> 4;
  const int row = t >> 2, c16 = (t & 3) * 16;

  // stage Q tile
  {
    const u16* src = Qb + (size_t)(qrowbase + n0 + row) * 256 + h * 64 + c16;
    *(uint4*)&QPs[row * 72 + c16] = *(const uint4*)src;
    *(uint4*)&QPs[row * 72 + c16 + 8] = *(const uint4*)(src + 8);
  }
  __syncthreads();
  short8 bq0 = *(const short8*)&QPs[(w * 16 + cl) * 72 + quad * 8];
  short8 bq1 = *(const short8*)&QPs[(w * 16 + cl) * 72 + quad * 8 + 32];

  float m_r = -1e30f, l_r = 0.f;
  f32x4 o[4];
#pragma unroll
  for (int i = 0; i < 4; ++i) o[i] = (f32x4){0.f, 0.f, 0.f, 0.f};

  const u16* Kg = Kb + (size_t)(krowbase + row) * 256 + h * 64 + c16;
  const u16* Vg = Vtb + ((size_t)(vz * NHEAD + h) * 64 + row) * NTOK + z * 1024 + c16;
  uint4 ka0 = *(const uint4*)Kg, ka1 = *(const uint4*)(Kg + 8);
  uint4 va0 = *(const uint4*)Vg, va1 = *(const uint4*)(Vg + 8);

  for (int tile = 0; tile < 16; ++tile) {
    __syncthreads();
    *(uint4*)&Ks[row * 72 + c16] = ka0;
    *(uint4*)&Ks[row * 72 + c16 + 8] = ka1;
    *(uint4*)&Vs[row * 72 + c16] = va0;
    *(uint4*)&Vs[row * 72 + c16 + 8] = va1;
    __syncthreads();
    if (tile < 15) {
      Kg += 64 * 256; Vg += 64;
      ka0 = *(const uint4*)Kg; ka1 = *(const uint4*)(Kg + 8);
      va0 = *(const uint4*)Vg; va1 = *(const uint4*)(Vg + 8);
    }

    // S^T strip: 64 keys x 16 q
    f32x4 sf[4];
#pragma unroll
    for (int kb = 0; kb < 4; ++kb) {
      short8 ak0 = *(const short8*)&Ks[(kb * 16 + cl) * 72 + quad * 8];
      short8 ak1 = *(const short8*)&Ks[(kb * 16 + cl) * 72 + quad * 8 + 32];
      f32x4 acc = (f32x4){0.f, 0.f, 0.f, 0.f};
      acc = __builtin_amdgcn_mfma_f32_16x16x32_bf16(ak0, bq0, acc, 0, 0, 0);
      acc = __builtin_amdgcn_mfma_f32_16x16x32_bf16(ak1, bq1, acc, 0, 0, 0);
      sf[kb] = acc;
    }

    // online softmax: each lane owns q = cl; keys spread over regs+quads
    float mx = sf[0][0];
#pragma unroll
    for (int kb = 0; kb < 4; ++kb)
#pragma unroll
      for (int r = 0; r < 4; ++r) mx = fmaxf(mx, sf[kb][r]);
    mx = fmaxf(mx, __shfl_xor(mx, 16));
    mx = fmaxf(mx, __shfl_xor(mx, 32));
    const float mn = fmaxf(m_r, mx);
    const float alpha = __expf(m_r - mn);
    m_r = mn;
    float rs = 0.f;
#pragma unroll
    for (int kb = 0; kb < 4; ++kb)
#pragma unroll
      for (int r = 0; r < 4; ++r) {
        const float p = __expf(sf[kb][r] - mn);
        sf[kb][r] = p; rs += p;
      }
    rs += __shfl_xor(rs, 16);
    rs += __shfl_xor(rs, 32);
    l_r = l_r * alpha + rs;
#pragma unroll
    for (int db = 0; db < 4; ++db) o[db] *= alpha;

    // P^T -> per-wave LDS region (rows w*16+cl), truncating bf16 pack
#pragma unroll
    for (int kb = 0; kb < 4; ++kb) {
      unsigned d0 = __builtin_amdgcn_perm(__float_as_uint(sf[kb][1]),
                                          __float_as_uint(sf[kb][0]), 0x07060302u);
      unsigned d1 = __builtin_amdgcn_perm(__float_as_uint(sf[kb][3]),
                                          __float_as_uint(sf[kb][2]), 0x07060302u);
      uint2 pk; pk.x = d0; pk.y = d1;
      *(uint2*)&QPs[(w * 16 + cl) * 72 + kb * 16 + quad * 4] = pk;
    }
    short8 bp0 = *(const short8*)&QPs[(w * 16 + cl) * 72 + quad * 8];
    short8 bp1 = *(const short8*)&QPs[(w * 16 + cl) * 72 + quad * 8 + 32];
#pragma unroll
    for (int db = 0; db < 4; ++db) {
      short8 av0 = *(const short8*)&Vs[(db * 16 + cl) * 72 + quad * 8];
      short8 av1 = *(const short8*)&Vs[(db * 16 + cl) * 72 + quad * 8 + 32];
      o[db] = __builtin_amdgcn_mfma_f32_16x16x32_bf16(av0, bp0, o[db], 0, 0, 0);
      o[db] = __builtin_amdgcn_mfma_f32_16x16x32_bf16(av1, bp1, o[db], 0, 0, 0);
    }
  }

  // store partials: o is O^T[d=db*16+quad*4+r][q=cl]
  const int rp = z * 65536 + y * 2048 + n0 + w * 16 + cl;
#pragma unroll
  for (int db = 0; db < 4; ++db) {
    ushort4 st;
    st.x = f2bf(o[db][0]); st.y = f2bf(o[db][1]);
    st.z = f2bf(o[db][2]); st.w = f2bf(o[db][3]);
    *(ushort4*)(Po + (size_t)rp * 64 + db * 16 + quad * 4) = st;
  }
  if (quad == 0) { Pm[rp] = m_r; Pl[rp] = l_r; }
}

// combine the 2 K-split partials -> bf16 unheads output
__global__ __launch_bounds__(256) void attn_combine_kernel(
    const u16* __restrict__ Po, const float* __restrict__ Pm,
    const float* __restrict__ Pl, u16* __restrict__ Ou)
{
  const int rowi = blockIdx.x * 4 + (threadIdx.x >> 6);
  const int lane = threadIdx.x & 63;
  const float m0 = Pm[rowi], m1 = Pm[65536 + rowi];
  const float l0 = Pl[rowi], l1 = Pl[65536 + rowi];
  const float M = fmaxf(m0, m1);
  const float e0 = __expf(m0 - M), e1 = __expf(m1 - M);
  const float inv = 1.f / (e0 * l0 + e1 * l1);
  const float o0 = bf2f(Po[(size_t)rowi * 64 + lane]);
  const float o1 = bf2f(Po[(size_t)65536 * 64 + (size_t)rowi * 64 + lane]);
  const float val = (e0 * o0 + e1 * o1) * inv;
  const int y = rowi >> 11, q = rowi & 2047;
  const int bz = y >> 2, h = y & 3;
  Ou[(size_t)(bz * NTOK + q) * 256 + h * 64 + lane] = f2bf(val);
}

// ---------------------------------------------------------------------------
// LayerNorm + exact GELU, bf16 in (M2,512) -> bf16 out
// ---------------------------------------------------------------------------
__global__ __launch_bounds__(256) void ln_gelu_kernel(
    const u16* __restrict__ Hm, const float* __restrict__ g,
    const float* __restrict__ be, u16* __restrict__ out)
{
  const int rowi = blockIdx.x * 4 + (threadIdx.x >> 6);
  const int lane = threadIdx.x & 63;
  const u16* row = Hm + (size_t)rowi * 512 + lane * 8;
  u16* orow = out + (size_t)rowi * 512 + lane * 8;
  uint4 raw = *(const uint4*)row;
  float x[8];
  const unsigned* rw = (const unsigned*)&raw;
#pragma unroll
  for (int i = 0; i < 4; ++i) {
    x[2 * i]     = bf2f((u16)rw[i]);
    x[2 * i + 1] = bf2f((u16)(rw[i] >> 16));
  }
  float s = 0.f;
#pragma unroll
  for (int i = 0; i < 8; ++i) s += x[i];
#pragma unroll
  for (int off = 32; off; off >>= 1) s += __shfl_xor(s, off);
  const float mean = s * (1.f / 512.f);
  float s2 = 0.f;
#pragma unroll
  for (int i = 0; i < 8; ++i) { const float d = x[i] - mean; s2 += d * d; }
#pragma unroll
  for (int off = 32; off; off >>= 1) s2 += __shfl_xor(s2, off);
  const float rstd = rsqrtf(s2 * (1.f / 512.f) + 1e-5f);
  unsigned ov[4];
#pragma unroll
  for (int i = 0; i < 4; ++i) {
    const int c = lane * 8 + 2 * i;
    const float y0 = (x[2 * i] - mean) * rstd * g[c] + be[c];
    const float y1 = (x[2 * i + 1] - mean) * rstd * g[c + 1] + be[c + 1];
    const float g0 = 0.5f * y0 * (1.f + erff(y0 * 0.70710678118654752f));
    const float g1 = 0.5f * y1 * (1.f + erff(y1 * 0.70710678118654752f));
    ov[i] = (unsigned)f2bf(g0) | ((unsigned)f2bf(g1) << 16);
  }
  *(uint4*)orow = *(uint4*)ov;
}

// fp32 (M,256) -> bf16
__global__ __launch_bounds__(256) void pack_desc_kernel(
    const float* __restrict__ in, u16* __restrict__ out)
{
  const size_t i4 = ((size_t)blockIdx.x * 256 + threadIdx.x) * 4;
  float4 v = *(const float4*)(in + i4);
  ushort4 o;
  o.x = f2bf(v.x); o.y = f2bf(v.y); o.z = f2bf(v.z); o.w = f2bf(v.w);
  *(ushort4*)(out + i4) = o;
}

__global__ __launch_bounds__(256) void pack_weights_kernel(
    const float* w0, const float* w1, const float* w2, const float* w3,
    const float* w4, const float* w5, const float* w6, const float* w7,
    const float* w8, u16* __restrict__ out)
{
  const int idx4 = (blockIdx.x * 256 + threadIdx.x) * 4;
  const float* src; int off;
  if      (idx4 <  196608) { src = w0; off = idx4; }
  else if (idx4 <  262144) { src = w1; off = idx4 - 196608; }
  else if (idx4 <  524288) { src = w2; off = idx4 - 262144; }
  else if (idx4 <  655360) { src = w3; off = idx4 - 524288; }
  else if (idx4 <  720896) { src = w4; off = idx4 - 655360; }
  else if (idx4 <  786432) { src = w5; off = idx4 - 720896; }
  else if (idx4 <  851968) { src = w6; off = idx4 - 786432; }
  else if (idx4 < 1114112) { src = w7; off = idx4 - 851968; }
  else                     { src = w8; off = idx4 - 1114112; }
  float4 v = *(const float4*)(src + off);
  ushort4 o;
  o.x = f2bf(v.x); o.y = f2bf(v.y); o.z = f2bf(v.z); o.w = f2bf(v.w);
  *(ushort4*)(out + idx4) = o;
}

// ---------------------------------------------------------------------------
static inline void launch_gemm(const u16* A, int lda, const u16* A2, int lda2,
                               int kSplit, const u16* W, const float* bias,
                               float oscale, const u16* resb, int ldrb,
                               float* Yf, int ldyf, u16* Yb, int ldyb,
                               int N, int K, hipStream_t s)
{
  dim3 g(N / 128, M2 / 128);
  hipLaunchKernelGGL(gemm_bf16_kernel, g, dim3(256), 0, s,
                     A, lda, A2, lda2, kSplit, W, bias, oscale,
                     resb, ldrb, Yf, ldyf, Yb, ldyb, K);
}

extern "C" void kernel_launch(void* const* d_in, const int* in_sizes, int n_in,
                              void* d_out, int out_size, void* d_ws, size_t ws_size,
                              hipStream_t stream) {
  const float* desc0  = (const float*)d_in[0];
  const float* desc1  = (const float*)d_in[1];
  const float* enc0   = (const float*)d_in[2];
  const float* enc1   = (const float*)d_in[3];
  const float* s_Wqkv = (const float*)d_in[4];
  const float* s_bqkv = (const float*)d_in[5];
  const float* s_Wout = (const float*)d_in[6];
  const float* s_bout = (const float*)d_in[7];
  const float* s_W1   = (const float*)d_in[8];
  const float* s_b1   = (const float*)d_in[9];
  const float* s_g    = (const float*)d_in[10];
  const float* s_be   = (const float*)d_in[11];
  const float* s_W2   = (const float*)d_in[12];
  const float* s_b2   = (const float*)d_in[13];
  const float* c_Wqk  = (const float*)d_in[14];
  const float* c_bqk  = (const float*)d_in[15];
  const float* c_Wv   = (const float*)d_in[16];
  const float* c_bv   = (const float*)d_in[17];
  const float* c_Wo   = (const float*)d_in[18];
  const float* c_bo   = (const float*)d_in[19];
  const float* c_W1   = (const float*)d_in[20];
  const float* c_b1   = (const float*)d_in[21];
  const float* c_g    = (const float*)d_in[22];
  const float* c_be   = (const float*)d_in[23];
  const float* c_W2   = (const float*)d_in[24];
  const float* c_b2   = (const float*)d_in[25];

  u16* U = (u16*)d_ws;
  // arena (units of NMu = 4 MB), total 24 units = 96 MB. Lifetimes disjoint:
  u16* descb = U + 0 * NMu;            // 2u (A..F)
  u16* qkvb  = U + 2 * NMu;            // 6u (phase A only)
  u16* ctxb  = U + 2 * NMu;            // 2u self-ctx (B,C) / cross mb (E,F)
  u16* msgb  = U + 4 * NMu;            // 2u (C,F)
  u16* Qu    = U + 8 * NMu;            // 2u self Q / cross qkb
  u16* Ku    = U + 10 * NMu;           // 2u self K / cross vb
  u16* Vu    = U + 12 * NMu;           // 2u self V staging (A)
  u16* Vt    = U + 14 * NMu;           // 2u transposed V (A,B / D,E)
  u16* hb2   = U + 12 * NMu;           // 4u ln-gelu out (C,F)
  u16* Po    = U + 16 * NMu;           // 4u attn partials (B,E)
  u16* hbufb = U + 16 * NMu;           // 4u ffn hidden (C,F)
  float* Pm  = (float*)(U + 20 * NMu); // 0.5 MB (B,E)
  float* Pl  = Pm + 2 * 65536;
  u16* s_b   = U + 21 * NMu;           // 2u self outputs (C..F)
  u16* wb    = U + 23 * NMu;           // 2.5 MB weights

  u16* Wqkvb = wb;
  u16* Woutb = wb + 196608;
  u16* W1b   = wb + 262144;
  u16* W2b   = wb + 524288;
  u16* cWqkb = wb + 655360;
  u16* cWvb  = wb + 720896;
  u16* cWob  = wb + 786432;
  u16* cW1b  = wb + 851968;
  u16* cW2b  = wb + 1114112;

  float* outf = (float*)d_out;         // 16384 x 256 fp32 (out0 || out1)

  const dim3 attn_grid(NTOK / 64, 32, 2);
  const dim3 tv_grid(NTOK / 64, NHEAD, 8);
  const int rope_blocks = (M2 * 128) / 256;
  const int lng_blocks  = M2 / 4;
  const int comb_blocks = 65536 / 4;
  const int desc_blocks = (int)(NMu / 4 / 256);
  const float cscale = 0.35355339059327373f;   // 8^-0.5, applied to both qk

  hipLaunchKernelGGL(pack_weights_kernel, dim3(1216), dim3(256), 0, stream,
                     s_Wqkv, s_Wout, s_W1, s_W2, c_Wqk, c_Wv, c_Wo, c_W1, c_W2, wb);
  hipLaunchKernelGGL(pack_desc_kernel, dim3(desc_blocks), dim3(256), 0, stream,
                     desc0, descb);
  hipLaunchKernelGGL(pack_desc_kernel, dim3(desc_blocks), dim3(256), 0, stream,
                     desc1, descb + NMu);

  // ---------------- self blocks (batched) ----------------
  launch_gemm(descb, 256, nullptr, 0, 1 << 30, Wqkvb, s_bqkv, 1.f,
              nullptr, 0, nullptr, 0, qkvb, 768, 768, 256, stream);
  hipLaunchKernelGGL(rope_repack_kernel, dim3(rope_blocks), dim3(256), 0, stream,
                     qkvb, enc0, enc1, Qu, Ku, Vu);
  hipLaunchKernelGGL(transpose_v_kernel, tv_grid, dim3(256), 0, stream, Vu, Vt);
  hipLaunchKernelGGL(attn2_kernel, attn_grid, dim3(256), 0, stream,
                     Qu, Ku, Vt, Po, Pm, Pl, 0);
  hipLaunchKernelGGL(attn_combine_kernel, dim3(comb_blocks), dim3(256), 0, stream,
                     Po, Pm, Pl, ctxb);
  launch_gemm(ctxb, 256, nullptr, 0, 1 << 30, Woutb, s_bout, 1.f,
              nullptr, 0, nullptr, 0, msgb, 256, 256, 256, stream);
  launch_gemm(descb, 256, msgb, 256, 256, W1b, s_b1, 1.f,
              nullptr, 0, nullptr, 0, hbufb, 512, 512, 512, stream);
  hipLaunchKernelGGL(ln_gelu_kernel, dim3(lng_blocks), dim3(256), 0, stream,
                     hbufb, s_g, s_be, hb2);
  launch_gemm(hb2, 512, nullptr, 0, 1 << 30, W2b, s_b2, 1.f,
              descb, 256, nullptr, 0, s_b, 256, 256, 512, stream);

  // ---------------- cross block (batched) ----------------
  u16* qkb = Qu;
  u16* vb  = Ku;
  launch_gemm(s_b, 256, nullptr, 0, 1 << 30, cWqkb, c_bqk, cscale,
              nullptr, 0, nullptr, 0, qkb, 256, 256, 256, stream);
  launch_gemm(s_b, 256, nullptr, 0, 1 << 30, cWvb, c_bv, 1.f,
              nullptr, 0, nullptr, 0, vb, 256, 256, 256, stream);
  hipLaunchKernelGGL(transpose_v_kernel, tv_grid, dim3(256), 0, stream, vb, Vt);
  hipLaunchKernelGGL(attn2_kernel, attn_grid, dim3(256), 0, stream,
                     qkb, qkb, Vt, Po, Pm, Pl, 1);
  hipLaunchKernelGGL(attn_combine_kernel, dim3(comb_blocks), dim3(256), 0, stream,
                     Po, Pm, Pl, ctxb);   // ctxb = mb (m0 || m1)
  launch_gemm(ctxb, 256, nullptr, 0, 1 << 30, cWob, c_bo, 1.f,
              nullptr, 0, nullptr, 0, msgb, 256, 256, 256, stream);
  launch_gemm(s_b, 256, msgb, 256, 256, cW1b, c_b1, 1.f,
              nullptr, 0, nullptr, 0, hbufb, 512, 512, 512, stream);
  hipLaunchKernelGGL(ln_gelu_kernel, dim3(lng_blocks), dim3(256), 0, stream,
                     hbufb, c_g, c_be, hb2);
  launch_gemm(hb2, 512, nullptr, 0, 1 << 30, cW2b, c_b2, 1.f,
              s_b, 256, outf, 256, nullptr, 0, 256, 512, stream);
}

// Round 5
// 449.778 us; speedup vs baseline: 12.7727x; 1.1045x over previous
//
#include <hip/hip_runtime.h>
#include <cstddef>

#define NTOK 2048
#define BDIM 4
#define DIM 256
#define NHEAD 4
#define MROWS 8192
#define M2 16384                        // both descriptors batched
#define NMu ((size_t)MROWS * DIM)       // 2,097,152 elems (bf16 unit = 4 MB)

typedef unsigned short u16;
typedef __attribute__((ext_vector_type(8))) short short8;
typedef __attribute__((ext_vector_type(4))) float f32x4;

__device__ __forceinline__ u16 f2bf(float x) {
  union { float f; unsigned u; } c; c.f = x;
  unsigned r = c.u + 0x7FFFu + ((c.u >> 16) & 1u);
  return (u16)(r >> 16);
}
__device__ __forceinline__ float bf2f(u16 u) {
  union { unsigned u; float f; } c; c.u = ((unsigned)u) << 16;
  return c.f;
}

__device__ __forceinline__ void glds16(const void* g, void* l) {
  __builtin_amdgcn_global_load_lds(
      (const __attribute__((address_space(1))) unsigned int*)g,
      (__attribute__((address_space(3))) unsigned int*)l, 16, 0, 0);
}

// ---------------------------------------------------------------------------
// bf16 MFMA GEMM, 128x128 tile (for N>=512): Y = (A @ W^T + bias)*oscale (+res)
// ---------------------------------------------------------------------------
__global__ __launch_bounds__(256) void gemm_bf16_kernel(
    const u16* __restrict__ A, int lda,
    const u16* __restrict__ A2, int lda2, int kSplit,
    const u16* __restrict__ W,
    const float* __restrict__ bias, float oscale,
    const u16* __restrict__ resb, int ldrb,
    float* __restrict__ Yf, int ldyf,
    u16* __restrict__ Yb, int ldyb,
    int K)
{
  __shared__ u16 As[128 * 32];
  __shared__ u16 Bs[128 * 32];
  const int t = threadIdx.x;
  const int m0 = blockIdx.y * 128, n0 = blockIdx.x * 128;
  const int r4 = t >> 2, c8 = (t & 3) * 8;
  const int lane = t & 63, w = t >> 6;
  const int cl = lane & 15, quad = lane >> 4;
  const int wm = (w >> 1) * 64, wn = (w & 1) * 64;

  f32x4 acc[4][4];
#pragma unroll
  for (int i = 0; i < 4; ++i)
#pragma unroll
    for (int j = 0; j < 4; ++j) acc[i][j] = (f32x4){0.f, 0.f, 0.f, 0.f};

  for (int k0 = 0; k0 < K; k0 += 32) {
    const u16* Ab; int la; int kk;
    if (k0 < kSplit) { Ab = A; la = lda; kk = k0; }
    else             { Ab = A2; la = lda2; kk = k0 - kSplit; }
    const u16* ag = Ab + (size_t)(m0 + r4) * la + kk + c8;
    const u16* bg = W + (size_t)(n0 + r4) * K + k0 + c8;
    __syncthreads();
    glds16(ag, &As[t * 8]);
    glds16(ag + (size_t)64 * la, &As[2048 + t * 8]);
    glds16(bg, &Bs[t * 8]);
    glds16(bg + (size_t)64 * K, &Bs[2048 + t * 8]);
    __syncthreads();

    short8 af[4], bfr[4];
#pragma unroll
    for (int i = 0; i < 4; ++i)
      af[i] = *(const short8*)&As[(wm + i * 16 + cl) * 32 + quad * 8];
#pragma unroll
    for (int i = 0; i < 4; ++i)
      bfr[i] = *(const short8*)&Bs[(wn + i * 16 + cl) * 32 + quad * 8];
#pragma unroll
    for (int mt = 0; mt < 4; ++mt)
#pragma unroll
      for (int nt = 0; nt < 4; ++nt)
        acc[mt][nt] = __builtin_amdgcn_mfma_f32_16x16x32_bf16(
            af[mt], bfr[nt], acc[mt][nt], 0, 0, 0);
  }

#pragma unroll
  for (int mt = 0; mt < 4; ++mt)
#pragma unroll
    for (int nt = 0; nt < 4; ++nt) {
      const int colg = n0 + wn + nt * 16 + cl;
      const float bs = bias[colg];
#pragma unroll
      for (int r = 0; r < 4; ++r) {
        const int rowg = m0 + wm + mt * 16 + quad * 4 + r;
        float v = (acc[mt][nt][r] + bs) * oscale;
        if (resb) v += bf2f(resb[(size_t)rowg * ldrb + colg]);
        if (Yf) Yf[(size_t)rowg * ldyf + colg] = v;
        if (Yb) Yb[(size_t)rowg * ldyb + colg] = f2bf(v);
      }
    }
}

// ---------------------------------------------------------------------------
// bf16 MFMA GEMM, 128x64 tile (for N==256 outputs -> 512 blocks = 2/CU)
// ---------------------------------------------------------------------------
__global__ __launch_bounds__(256) void gemm_n64_kernel(
    const u16* __restrict__ A, int lda,
    const u16* __restrict__ A2, int lda2, int kSplit,
    const u16* __restrict__ W,
    const float* __restrict__ bias, float oscale,
    const u16* __restrict__ resb, int ldrb,
    float* __restrict__ Yf, int ldyf,
    u16* __restrict__ Yb, int ldyb,
    int K)
{
  __shared__ u16 As[128 * 32];
  __shared__ u16 Bs[64 * 32];
  const int t = threadIdx.x;
  const int m0 = blockIdx.y * 128, n0 = blockIdx.x * 64;
  const int r4 = t >> 2, c8 = (t & 3) * 8;
  const int lane = t & 63, w = t >> 6;
  const int cl = lane & 15, quad = lane >> 4;
  const int wm = (w >> 1) * 64, wn = (w & 1) * 32;

  f32x4 acc[4][2];
#pragma unroll
  for (int i = 0; i < 4; ++i)
#pragma unroll
    for (int j = 0; j < 2; ++j) acc[i][j] = (f32x4){0.f, 0.f, 0.f, 0.f};

  for (int k0 = 0; k0 < K; k0 += 32) {
    const u16* Ab; int la; int kk;
    if (k0 < kSplit) { Ab = A; la = lda; kk = k0; }
    else             { Ab = A2; la = lda2; kk = k0 - kSplit; }
    const u16* ag = Ab + (size_t)(m0 + r4) * la + kk + c8;
    const u16* bg = W + (size_t)(n0 + r4) * K + k0 + c8;
    __syncthreads();
    glds16(ag, &As[t * 8]);
    glds16(ag + (size_t)64 * la, &As[2048 + t * 8]);
    glds16(bg, &Bs[t * 8]);
    __syncthreads();

    short8 af[4], bfr[2];
#pragma unroll
    for (int i = 0; i < 4; ++i)
      af[i] = *(const short8*)&As[(wm + i * 16 + cl) * 32 + quad * 8];
#pragma unroll
    for (int j = 0; j < 2; ++j)
      bfr[j] = *(const short8*)&Bs[(wn + j * 16 + cl) * 32 + quad * 8];
#pragma unroll
    for (int mt = 0; mt < 4; ++mt)
#pragma unroll
      for (int nt = 0; nt < 2; ++nt)
        acc[mt][nt] = __builtin_amdgcn_mfma_f32_16x16x32_bf16(
            af[mt], bfr[nt], acc[mt][nt], 0, 0, 0);
  }

#pragma unroll
  for (int mt = 0; mt < 4; ++mt)
#pragma unroll
    for (int nt = 0; nt < 2; ++nt) {
      const int colg = n0 + wn + nt * 16 + cl;
      const float bs = bias[colg];
#pragma unroll
      for (int r = 0; r < 4; ++r) {
        const int rowg = m0 + wm + mt * 16 + quad * 4 + r;
        float v = (acc[mt][nt][r] + bs) * oscale;
        if (resb) v += bf2f(resb[(size_t)rowg * ldrb + colg]);
        if (Yf) Yf[(size_t)rowg * ldyf + colg] = v;
        if (Yb) Yb[(size_t)rowg * ldyb + colg] = f2bf(v);
      }
    }
}

// ---------------------------------------------------------------------------
// RoPE batched over both descriptors. qkv (M2,768) -> Qu (scaled 0.125), Ku,
// Vu, all bf16 unheads (M2,256).
// ---------------------------------------------------------------------------
__global__ __launch_bounds__(256) void rope_repack_kernel(
    const u16* __restrict__ qkv, const float* __restrict__ enc0,
    const float* __restrict__ enc1,
    u16* __restrict__ Q, u16* __restrict__ K, u16* __restrict__ V)
{
  const int idx = blockIdx.x * blockDim.x + threadIdx.x;  // < M2*4*32
  const int i = idx & 31;
  const int h = (idx >> 5) & 3;
  const int m = idx >> 7;                 // 0..16383
  const int half = m >> 13;
  const int lm = m & (MROWS - 1);
  const float* enc = half ? enc1 : enc0;
  const u16* src = qkv + (size_t)m * 768 + h * 192 + i * 6;
  const unsigned a0 = *(const unsigned*)(src);
  const unsigned a1 = *(const unsigned*)(src + 2);
  const unsigned a2 = *(const unsigned*)(src + 4);
  const float q0 = bf2f((u16)a0), k0 = bf2f((u16)(a0 >> 16));
  const float v0 = bf2f((u16)a1), q1 = bf2f((u16)(a1 >> 16));
  const float k1 = bf2f((u16)a2), v1 = bf2f((u16)(a2 >> 16));
  const float c = enc[(size_t)lm * 64 + 2 * i];
  const float s = enc[(size_t)MROWS * 64 + (size_t)lm * 64 + 2 * i];
  const size_t o = (size_t)m * 256 + h * 64 + 2 * i;
  *(unsigned*)(Q + o) = (unsigned)f2bf((q0 * c - q1 * s) * 0.125f) |
                        ((unsigned)f2bf((q1 * c + q0 * s) * 0.125f) << 16);
  *(unsigned*)(K + o) = (unsigned)f2bf(k0 * c - k1 * s) |
                        ((unsigned)f2bf(k1 * c + k0 * s) << 16);
  *(unsigned*)(V + o) = (unsigned)f2bf(v0) | ((unsigned)f2bf(v1) << 16);
}

// bf16 unheads (M2,256) -> bf16 transposed head-major (8,H,64,2048)
__global__ __launch_bounds__(256) void transpose_v_kernel(
    const u16* __restrict__ in, u16* __restrict__ out)
{
  __shared__ u16 Tl[64][72];
  const int bz = blockIdx.z, h = blockIdx.y;
  const int n0 = blockIdx.x * 64;
  const int t = threadIdx.x;
  {
    const int row = t >> 2, c16 = (t & 3) * 16;
    const u16* src = in + (size_t)(bz * NTOK + n0 + row) * 256 + h * 64 + c16;
    *(uint4*)&Tl[row][c16] = *(const uint4*)src;
    *(uint4*)&Tl[row][c16 + 8] = *(const uint4*)(src + 8);
  }
  __syncthreads();
  const int d = t >> 2, qr = t & 3;
  union { u16 u[16]; uint4 v[2]; } pk;
#pragma unroll
  for (int j = 0; j < 16; ++j) pk.u[j] = Tl[qr * 16 + j][d];
  u16* dst = out + ((size_t)((bz * NHEAD + h) * 64 + d)) * NTOK + n0 + qr * 16;
  *(uint4*)dst = pk.v[0];
  *(uint4*)(dst + 8) = pk.v[1];
}

// ---------------------------------------------------------------------------
// MFMA flash attention v3: S^T formulation, 128-q blocks, 32 q per wave
// (two 16-q columns sharing every K/V fragment read). K-split z=2.
// grid (16, 32, 2), block 256 = 4 waves. LDS 36.9 KB -> 4 blocks/CU.
// ---------------------------------------------------------------------------
__global__ __launch_bounds__(256, 4) void attn3_kernel(
    const u16* __restrict__ Qb, const u16* __restrict__ Kb,
    const u16* __restrict__ Vtb,
    u16* __restrict__ Po, float* __restrict__ Pm, float* __restrict__ Pl,
    int cross)
{
  __shared__ u16 Ks[64 * 72];
  __shared__ u16 Vs[64 * 72];
  __shared__ u16 QPs[128 * 72];  // Q tile at start, then P^T region
  const int y = blockIdx.y, z = blockIdx.z;
  const int h2 = y >> 4, b = (y >> 2) & 3, h = y & 3;
  const int kh = cross ? (1 - h2) : h2;
  const int qrowbase = (h2 * 4 + b) * NTOK;
  const int krowbase = (kh * 4 + b) * NTOK + z * 1024;
  const int vz = kh * 4 + b;
  const int n0 = blockIdx.x * 128;
  const int t = threadIdx.x, lane = t & 63, w = t >> 6;
  const int cl = lane & 15, quad = lane >> 4;

  // stage Q tile (128 x 64 bf16)
  {
    const int row = t >> 1, c32 = (t & 1) * 32;
    const u16* src = Qb + (size_t)(qrowbase + n0 + row) * 256 + h * 64 + c32;
    uint4 v0 = *(const uint4*)src;
    uint4 v1 = *(const uint4*)(src + 8);
    uint4 v2 = *(const uint4*)(src + 16);
    uint4 v3 = *(const uint4*)(src + 24);
    u16* d = &QPs[row * 72 + c32];
    *(uint4*)d = v0; *(uint4*)(d + 8) = v1;
    *(uint4*)(d + 16) = v2; *(uint4*)(d + 24) = v3;
  }
  __syncthreads();
  const int q0 = w * 32;
  short8 bq[2][2];
#pragma unroll
  for (int c = 0; c < 2; ++c) {
    bq[c][0] = *(const short8*)&QPs[(q0 + c * 16 + cl) * 72 + quad * 8];
    bq[c][1] = *(const short8*)&QPs[(q0 + c * 16 + cl) * 72 + quad * 8 + 32];
  }

  float m_r[2] = {-1e30f, -1e30f}, l_r[2] = {0.f, 0.f};
  f32x4 o[2][4];
#pragma unroll
  for (int c = 0; c < 2; ++c)
#pragma unroll
    for (int i = 0; i < 4; ++i) o[c][i] = (f32x4){0.f, 0.f, 0.f, 0.f};

  const int srow = t >> 2, sc16 = (t & 3) * 16;
  const u16* Kg = Kb + (size_t)(krowbase + srow) * 256 + h * 64 + sc16;
  const u16* Vg = Vtb + ((size_t)(vz * NHEAD + h) * 64 + srow) * NTOK + z * 1024 + sc16;
  uint4 ka0 = *(const uint4*)Kg, ka1 = *(const uint4*)(Kg + 8);
  uint4 va0 = *(const uint4*)Vg, va1 = *(const uint4*)(Vg + 8);

  for (int tile = 0; tile < 16; ++tile) {
    __syncthreads();   // everyone done reading prev K/V tile (incl. P-phase)
    *(uint4*)&Ks[srow * 72 + sc16] = ka0;
    *(uint4*)&Ks[srow * 72 + sc16 + 8] = ka1;
    *(uint4*)&Vs[srow * 72 + sc16] = va0;
    *(uint4*)&Vs[srow * 72 + sc16 + 8] = va1;
    __syncthreads();
    if (tile < 15) {
      Kg += 64 * 256; Vg += 64;
      ka0 = *(const uint4*)Kg; ka1 = *(const uint4*)(Kg + 8);
      va0 = *(const uint4*)Vg; va1 = *(const uint4*)(Vg + 8);
    }

    // S^T strip: 64 keys x 32 q; K fragments shared by both q-columns
    f32x4 sf[2][4];
#pragma unroll
    for (int kb = 0; kb < 4; ++kb) {
      short8 ak0 = *(const short8*)&Ks[(kb * 16 + cl) * 72 + quad * 8];
      short8 ak1 = *(const short8*)&Ks[(kb * 16 + cl) * 72 + quad * 8 + 32];
#pragma unroll
      for (int c = 0; c < 2; ++c) {
        f32x4 acc = (f32x4){0.f, 0.f, 0.f, 0.f};
        acc = __builtin_amdgcn_mfma_f32_16x16x32_bf16(ak0, bq[c][0], acc, 0, 0, 0);
        acc = __builtin_amdgcn_mfma_f32_16x16x32_bf16(ak1, bq[c][1], acc, 0, 0, 0);
        sf[c][kb] = acc;
      }
    }

    // online softmax per column (lane owns q = q0 + c*16 + cl)
#pragma unroll
    for (int c = 0; c < 2; ++c) {
      float mx = sf[c][0][0];
#pragma unroll
      for (int kb = 0; kb < 4; ++kb)
#pragma unroll
        for (int r = 0; r < 4; ++r) mx = fmaxf(mx, sf[c][kb][r]);
      mx = fmaxf(mx, __shfl_xor(mx, 16));
      mx = fmaxf(mx, __shfl_xor(mx, 32));
      const float mn = fmaxf(m_r[c], mx);
      const float alpha = __expf(m_r[c] - mn);
      m_r[c] = mn;
      float rs = 0.f;
#pragma unroll
      for (int kb = 0; kb < 4; ++kb)
#pragma unroll
        for (int r = 0; r < 4; ++r) {
          const float p = __expf(sf[c][kb][r] - mn);
          sf[c][kb][r] = p; rs += p;
        }
      rs += __shfl_xor(rs, 16);
      rs += __shfl_xor(rs, 32);
      l_r[c] = l_r[c] * alpha + rs;
#pragma unroll
      for (int db = 0; db < 4; ++db) o[c][db] *= alpha;
      // P^T row (q0+c*16+cl), keys contiguous
#pragma unroll
      for (int kb = 0; kb < 4; ++kb) {
        unsigned d0 = __builtin_amdgcn_perm(__float_as_uint(sf[c][kb][1]),
                                            __float_as_uint(sf[c][kb][0]), 0x07060302u);
        unsigned d1 = __builtin_amdgcn_perm(__float_as_uint(sf[c][kb][3]),
                                            __float_as_uint(sf[c][kb][2]), 0x07060302u);
        uint2 pk; pk.x = d0; pk.y = d1;
        *(uint2*)&QPs[(q0 + c * 16 + cl) * 72 + kb * 16 + quad * 4] = pk;
      }
    }

    // O^T += V^T P^T; V fragments shared by both q-columns
    short8 bp[2][2];
#pragma unroll
    for (int c = 0; c < 2; ++c) {
      bp[c][0] = *(const short8*)&QPs[(q0 + c * 16 + cl) * 72 + quad * 8];
      bp[c][1] = *(const short8*)&QPs[(q0 + c * 16 + cl) * 72 + quad * 8 + 32];
    }
#pragma unroll
    for (int db = 0; db < 4; ++db) {
      short8 av0 = *(const short8*)&Vs[(db * 16 + cl) * 72 + quad * 8];
      short8 av1 = *(const short8*)&Vs[(db * 16 + cl) * 72 + quad * 8 + 32];
#pragma unroll
      for (int c = 0; c < 2; ++c) {
        o[c][db] = __builtin_amdgcn_mfma_f32_16x16x32_bf16(av0, bp[c][0], o[c][db], 0, 0, 0);
        o[c][db] = __builtin_amdgcn_mfma_f32_16x16x32_bf16(av1, bp[c][1], o[c][db], 0, 0, 0);
      }
    }
  }

  // store partials
#pragma unroll
  for (int c = 0; c < 2; ++c) {
    const int rp = z * 65536 + y * 2048 + n0 + q0 + c * 16 + cl;
#pragma unroll
    for (int db = 0; db < 4; ++db) {
      ushort4 st;
      st.x = f2bf(o[c][db][0]); st.y = f2bf(o[c][db][1]);
      st.z = f2bf(o[c][db][2]); st.w = f2bf(o[c][db][3]);
      *(ushort4*)(Po + (size_t)rp * 64 + db * 16 + quad * 4) = st;
    }
    if (quad == 0) { Pm[rp] = m_r[c]; Pl[rp] = l_r[c]; }
  }
}

// combine the 2 K-split partials -> bf16 unheads output
__global__ __launch_bounds__(256) void attn_combine_kernel(
    const u16* __restrict__ Po, const float* __restrict__ Pm,
    const float* __restrict__ Pl, u16* __restrict__ Ou)
{
  const int rowi = blockIdx.x * 4 + (threadIdx.x >> 6);
  const int lane = threadIdx.x & 63;
  const float m0 = Pm[rowi], m1 = Pm[65536 + rowi];
  const float l0 = Pl[rowi], l1 = Pl[65536 + rowi];
  const float M = fmaxf(m0, m1);
  const float e0 = __expf(m0 - M), e1 = __expf(m1 - M);
  const float inv = 1.f / (e0 * l0 + e1 * l1);
  const float o0 = bf2f(Po[(size_t)rowi * 64 + lane]);
  const float o1 = bf2f(Po[(size_t)65536 * 64 + (size_t)rowi * 64 + lane]);
  const float val = (e0 * o0 + e1 * o1) * inv;
  const int y = rowi >> 11, q = rowi & 2047;
  const int bz = y >> 2, h = y & 3;
  Ou[(size_t)(bz * NTOK + q) * 256 + h * 64 + lane] = f2bf(val);
}

// ---------------------------------------------------------------------------
// LayerNorm + exact GELU, bf16 in (M2,512) -> bf16 out
// ---------------------------------------------------------------------------
__global__ __launch_bounds__(256) void ln_gelu_kernel(
    const u16* __restrict__ Hm, const float* __restrict__ g,
    const float* __restrict__ be, u16* __restrict__ out)
{
  const int rowi = blockIdx.x * 4 + (threadIdx.x >> 6);
  const int lane = threadIdx.x & 63;
  const u16* row = Hm + (size_t)rowi * 512 + lane * 8;
  u16* orow = out + (size_t)rowi * 512 + lane * 8;
  uint4 raw = *(const uint4*)row;
  float x[8];
  const unsigned* rw = (const unsigned*)&raw;
#pragma unroll
  for (int i = 0; i < 4; ++i) {
    x[2 * i]     = bf2f((u16)rw[i]);
    x[2 * i + 1] = bf2f((u16)(rw[i] >> 16));
  }
  float s = 0.f;
#pragma unroll
  for (int i = 0; i < 8; ++i) s += x[i];
#pragma unroll
  for (int off = 32; off; off >>= 1) s += __shfl_xor(s, off);
  const float mean = s * (1.f / 512.f);
  float s2 = 0.f;
#pragma unroll
  for (int i = 0; i < 8; ++i) { const float d = x[i] - mean; s2 += d * d; }
#pragma unroll
  for (int off = 32; off; off >>= 1) s2 += __shfl_xor(s2, off);
  const float rstd = rsqrtf(s2 * (1.f / 512.f) + 1e-5f);
  unsigned ov[4];
#pragma unroll
  for (int i = 0; i < 4; ++i) {
    const int c = lane * 8 + 2 * i;
    const float y0 = (x[2 * i] - mean) * rstd * g[c] + be[c];
    const float y1 = (x[2 * i + 1] - mean) * rstd * g[c + 1] + be[c + 1];
    const float g0 = 0.5f * y0 * (1.f + erff(y0 * 0.70710678118654752f));
    const float g1 = 0.5f * y1 * (1.f + erff(y1 * 0.70710678118654752f));
    ov[i] = (unsigned)f2bf(g0) | ((unsigned)f2bf(g1) << 16);
  }
  *(uint4*)orow = *(uint4*)ov;
}

// fp32 (2 x M,256) -> bf16, both descriptors in one dispatch
__global__ __launch_bounds__(256) void pack_desc_kernel(
    const float* __restrict__ in0, const float* __restrict__ in1,
    u16* __restrict__ out)
{
  const float* in = blockIdx.y ? in1 : in0;
  const size_t i4 = ((size_t)blockIdx.x * 256 + threadIdx.x) * 4;
  float4 v = *(const float4*)(in + i4);
  ushort4 o;
  o.x = f2bf(v.x); o.y = f2bf(v.y); o.z = f2bf(v.z); o.w = f2bf(v.w);
  *(ushort4*)(out + blockIdx.y * NMu + i4) = o;
}

__global__ __launch_bounds__(256) void pack_weights_kernel(
    const float* w0, const float* w1, const float* w2, const float* w3,
    const float* w4, const float* w5, const float* w6, const float* w7,
    const float* w8, u16* __restrict__ out)
{
  const int idx4 = (blockIdx.x * 256 + threadIdx.x) * 4;
  const float* src; int off;
  if      (idx4 <  196608) { src = w0; off = idx4; }
  else if (idx4 <  262144) { src = w1; off = idx4 - 196608; }
  else if (idx4 <  524288) { src = w2; off = idx4 - 262144; }
  else if (idx4 <  655360) { src = w3; off = idx4 - 524288; }
  else if (idx4 <  720896) { src = w4; off = idx4 - 655360; }
  else if (idx4 <  786432) { src = w5; off = idx4 - 720896; }
  else if (idx4 <  851968) { src = w6; off = idx4 - 786432; }
  else if (idx4 < 1114112) { src = w7; off = idx4 - 851968; }
  else                     { src = w8; off = idx4 - 1114112; }
  float4 v = *(const float4*)(src + off);
  ushort4 o;
  o.x = f2bf(v.x); o.y = f2bf(v.y); o.z = f2bf(v.z); o.w = f2bf(v.w);
  *(ushort4*)(out + idx4) = o;
}

// ---------------------------------------------------------------------------
static inline void launch_gemm(const u16* A, int lda, const u16* A2, int lda2,
                               int kSplit, const u16* W, const float* bias,
                               float oscale, const u16* resb, int ldrb,
                               float* Yf, int ldyf, u16* Yb, int ldyb,
                               int N, int K, hipStream_t s)
{
  if (N == 256) {
    dim3 g(N / 64, M2 / 128);
    hipLaunchKernelGGL(gemm_n64_kernel, g, dim3(256), 0, s,
                       A, lda, A2, lda2, kSplit, W, bias, oscale,
                       resb, ldrb, Yf, ldyf, Yb, ldyb, K);
  } else {
    dim3 g(N / 128, M2 / 128);
    hipLaunchKernelGGL(gemm_bf16_kernel, g, dim3(256), 0, s,
                       A, lda, A2, lda2, kSplit, W, bias, oscale,
                       resb, ldrb, Yf, ldyf, Yb, ldyb, K);
  }
}

extern "C" void kernel_launch(void* const* d_in, const int* in_sizes, int n_in,
                              void* d_out, int out_size, void* d_ws, size_t ws_size,
                              hipStream_t stream) {
  const float* desc0  = (const float*)d_in[0];
  const float* desc1  = (const float*)d_in[1];
  const float* enc0   = (const float*)d_in[2];
  const float* enc1   = (const float*)d_in[3];
  const float* s_Wqkv = (const float*)d_in[4];
  const float* s_bqkv = (const float*)d_in[5];
  const float* s_Wout = (const float*)d_in[6];
  const float* s_bout = (const float*)d_in[7];
  const float* s_W1   = (const float*)d_in[8];
  const float* s_b1   = (const float*)d_in[9];
  const float* s_g    = (const float*)d_in[10];
  const float* s_be   = (const float*)d_in[11];
  const float* s_W2   = (const float*)d_in[12];
  const float* s_b2   = (const float*)d_in[13];
  const float* c_Wqk  = (const float*)d_in[14];
  const float* c_bqk  = (const float*)d_in[15];
  const float* c_Wv   = (const float*)d_in[16];
  const float* c_bv   = (const float*)d_in[17];
  const float* c_Wo   = (const float*)d_in[18];
  const float* c_bo   = (const float*)d_in[19];
  const float* c_W1   = (const float*)d_in[20];
  const float* c_b1   = (const float*)d_in[21];
  const float* c_g    = (const float*)d_in[22];
  const float* c_be   = (const float*)d_in[23];
  const float* c_W2   = (const float*)d_in[24];
  const float* c_b2   = (const float*)d_in[25];

  u16* U = (u16*)d_ws;
  u16* descb = U + 0 * NMu;
  u16* qkvb  = U + 2 * NMu;
  u16* ctxb  = U + 2 * NMu;
  u16* msgb  = U + 4 * NMu;
  u16* Qu    = U + 8 * NMu;
  u16* Ku    = U + 10 * NMu;
  u16* Vu    = U + 12 * NMu;
  u16* Vt    = U + 14 * NMu;
  u16* hb2   = U + 12 * NMu;
  u16* Po    = U + 16 * NMu;
  u16* hbufb = U + 16 * NMu;
  float* Pm  = (float*)(U + 20 * NMu);
  float* Pl  = Pm + 2 * 65536;
  u16* s_b   = U + 21 * NMu;
  u16* wb    = U + 23 * NMu;

  u16* Wqkvb = wb;
  u16* Woutb = wb + 196608;
  u16* W1b   = wb + 262144;
  u16* W2b   = wb + 524288;
  u16* cWqkb = wb + 655360;
  u16* cWvb  = wb + 720896;
  u16* cWob  = wb + 786432;
  u16* cW1b  = wb + 851968;
  u16* cW2b  = wb + 1114112;

  float* outf = (float*)d_out;

  const dim3 attn_grid(NTOK / 128, 32, 2);
  const dim3 tv_grid(NTOK / 64, NHEAD, 8);
  const int rope_blocks = (M2 * 128) / 256;
  const int lng_blocks  = M2 / 4;
  const int comb_blocks = 65536 / 4;
  const dim3 desc_grid((unsigned)(NMu / 4 / 256), 2);
  const float cscale = 0.35355339059327373f;   // 8^-0.5

  hipLaunchKernelGGL(pack_weights_kernel, dim3(1216), dim3(256), 0, stream,
                     s_Wqkv, s_Wout, s_W1, s_W2, c_Wqk, c_Wv, c_Wo, c_W1, c_W2, wb);
  hipLaunchKernelGGL(pack_desc_kernel, desc_grid, dim3(256), 0, stream,
                     desc0, desc1, descb);

  // ---------------- self blocks (batched) ----------------
  launch_gemm(descb, 256, nullptr, 0, 1 << 30, Wqkvb, s_bqkv, 1.f,
              nullptr, 0, nullptr, 0, qkvb, 768, 768, 256, stream);
  hipLaunchKernelGGL(rope_repack_kernel, dim3(rope_blocks), dim3(256), 0, stream,
                     qkvb, enc0, enc1, Qu, Ku, Vu);
  hipLaunchKernelGGL(transpose_v_kernel, tv_grid, dim3(256), 0, stream, Vu, Vt);
  hipLaunchKernelGGL(attn3_kernel, attn_grid, dim3(256), 0, stream,
                     Qu, Ku, Vt, Po, Pm, Pl, 0);
  hipLaunchKernelGGL(attn_combine_kernel, dim3(comb_blocks), dim3(256), 0, stream,
                     Po, Pm, Pl, ctxb);
  launch_gemm(ctxb, 256, nullptr, 0, 1 << 30, Woutb, s_bout, 1.f,
              nullptr, 0, nullptr, 0, msgb, 256, 256, 256, stream);
  launch_gemm(descb, 256, msgb, 256, 256, W1b, s_b1, 1.f,
              nullptr, 0, nullptr, 0, hbufb, 512, 512, 512, stream);
  hipLaunchKernelGGL(ln_gelu_kernel, dim3(lng_blocks), dim3(256), 0, stream,
                     hbufb, s_g, s_be, hb2);
  launch_gemm(hb2, 512, nullptr, 0, 1 << 30, W2b, s_b2, 1.f,
              descb, 256, nullptr, 0, s_b, 256, 256, 512, stream);

  // ---------------- cross block (batched) ----------------
  u16* qkb = Qu;
  u16* vb  = Ku;
  launch_gemm(s_b, 256, nullptr, 0, 1 << 30, cWqkb, c_bqk, cscale,
              nullptr, 0, nullptr, 0, qkb, 256, 256, 256, stream);
  launch_gemm(s_b, 256, nullptr, 0, 1 << 30, cWvb, c_bv, 1.f,
              nullptr, 0, nullptr, 0, vb, 256, 256, 256, stream);
  hipLaunchKernelGGL(transpose_v_kernel, tv_grid, dim3(256), 0, stream, vb, Vt);
  hipLaunchKernelGGL(attn3_kernel, attn_grid, dim3(256), 0, stream,
                     qkb, qkb, Vt, Po, Pm, Pl, 1);
  hipLaunchKernelGGL(attn_combine_kernel, dim3(comb_blocks), dim3(256), 0, stream,
                     Po, Pm, Pl, ctxb);
  launch_gemm(ctxb, 256, nullptr, 0, 1 << 30, cWob, c_bo, 1.f,
              nullptr, 0, nullptr, 0, msgb, 256, 256, 256, stream);
  launch_gemm(s_b, 256, msgb, 256, 256, cW1b, c_b1, 1.f,
              nullptr, 0, nullptr, 0, hbufb, 512, 512, 512, stream);
  hipLaunchKernelGGL(ln_gelu_kernel, dim3(lng_blocks), dim3(256), 0, stream,
                     hbufb, c_g, c_be, hb2);
  launch_gemm(hb2, 512, nullptr, 0, 1 << 30, cW2b, c_b2, 1.f,
              s_b, 256, outf, 256, nullptr, 0, 256, 512, stream);
}

// Round 6
// 441.960 us; speedup vs baseline: 12.9987x; 1.0177x over previous
//
#include <hip/hip_runtime.h>
#include <cstddef>

#define NTOK 2048
#define BDIM 4
#define DIM 256
#define NHEAD 4
#define MROWS 8192
#define M2 16384                        // both descriptors batched
#define NMu ((size_t)MROWS * DIM)       // 2,097,152 elems (bf16 unit = 4 MB)

typedef unsigned short u16;
typedef __attribute__((ext_vector_type(8))) short short8;
typedef __attribute__((ext_vector_type(4))) float f32x4;

__device__ __forceinline__ u16 f2bf(float x) {
  union { float f; unsigned u; } c; c.f = x;
  unsigned r = c.u + 0x7FFFu + ((c.u >> 16) & 1u);
  return (u16)(r >> 16);
}
__device__ __forceinline__ float bf2f(u16 u) {
  union { unsigned u; float f; } c; c.u = ((unsigned)u) << 16;
  return c.f;
}

__device__ __forceinline__ void glds16(const void* g, void* l) {
  __builtin_amdgcn_global_load_lds(
      (const __attribute__((address_space(1))) unsigned int*)g,
      (__attribute__((address_space(3))) unsigned int*)l, 16, 0, 0);
}

// ---------------------------------------------------------------------------
// bf16 MFMA GEMM, 128x128 tile. Y = (A @ W^T + bias)*oscale, with:
//  - A split at kSplit between A/A2 (concat inputs)
//  - N split at nsplit: bias0/os0/Yb0 for cols<nsplit, bias1/os1/Yb1 after
// ---------------------------------------------------------------------------
__global__ __launch_bounds__(256) void gemm_bf16_kernel(
    const u16* __restrict__ A, int lda,
    const u16* __restrict__ A2, int lda2, int kSplit,
    const u16* __restrict__ W,
    const float* __restrict__ bias0, const float* __restrict__ bias1,
    int nsplit, float os0, float os1,
    u16* __restrict__ Yb0, int ldy0,
    u16* __restrict__ Yb1, int ldy1,
    int K)
{
  __shared__ u16 As[128 * 32];
  __shared__ u16 Bs[128 * 32];
  const int t = threadIdx.x;
  const int m0 = blockIdx.y * 128, n0 = blockIdx.x * 128;
  const int r4 = t >> 2, c8 = (t & 3) * 8;
  const int lane = t & 63, w = t >> 6;
  const int cl = lane & 15, quad = lane >> 4;
  const int wm = (w >> 1) * 64, wn = (w & 1) * 64;

  f32x4 acc[4][4];
#pragma unroll
  for (int i = 0; i < 4; ++i)
#pragma unroll
    for (int j = 0; j < 4; ++j) acc[i][j] = (f32x4){0.f, 0.f, 0.f, 0.f};

  for (int k0 = 0; k0 < K; k0 += 32) {
    const u16* Ab; int la; int kk;
    if (k0 < kSplit) { Ab = A; la = lda; kk = k0; }
    else             { Ab = A2; la = lda2; kk = k0 - kSplit; }
    const u16* ag = Ab + (size_t)(m0 + r4) * la + kk + c8;
    const u16* bg = W + (size_t)(n0 + r4) * K + k0 + c8;
    __syncthreads();
    glds16(ag, &As[t * 8]);
    glds16(ag + (size_t)64 * la, &As[2048 + t * 8]);
    glds16(bg, &Bs[t * 8]);
    glds16(bg + (size_t)64 * K, &Bs[2048 + t * 8]);
    __syncthreads();

    short8 af[4], bfr[4];
#pragma unroll
    for (int i = 0; i < 4; ++i)
      af[i] = *(const short8*)&As[(wm + i * 16 + cl) * 32 + quad * 8];
#pragma unroll
    for (int i = 0; i < 4; ++i)
      bfr[i] = *(const short8*)&Bs[(wn + i * 16 + cl) * 32 + quad * 8];
#pragma unroll
    for (int mt = 0; mt < 4; ++mt)
#pragma unroll
      for (int nt = 0; nt < 4; ++nt)
        acc[mt][nt] = __builtin_amdgcn_mfma_f32_16x16x32_bf16(
            af[mt], bfr[nt], acc[mt][nt], 0, 0, 0);
  }

#pragma unroll
  for (int mt = 0; mt < 4; ++mt)
#pragma unroll
    for (int nt = 0; nt < 4; ++nt) {
      const int colg = n0 + wn + nt * 16 + cl;
      const bool first = colg < nsplit;
      const int c2 = first ? colg : colg - nsplit;
      const float bs = first ? bias0[c2] : bias1[c2];
      const float os = first ? os0 : os1;
      u16* yb = first ? Yb0 : Yb1;
      const int ly = first ? ldy0 : ldy1;
#pragma unroll
      for (int r = 0; r < 4; ++r) {
        const int rowg = m0 + wm + mt * 16 + quad * 4 + r;
        yb[(size_t)rowg * ly + c2] = f2bf((acc[mt][nt][r] + bs) * os);
      }
    }
}

// ---------------------------------------------------------------------------
// bf16 MFMA GEMM, 64x64 tile (N==256 GEMMs -> 1024 blocks = 4/CU).
// ---------------------------------------------------------------------------
__global__ __launch_bounds__(256) void gemm64_kernel(
    const u16* __restrict__ A, int lda,
    const u16* __restrict__ W,
    const float* __restrict__ bias,
    const u16* __restrict__ resb, int ldrb,
    float* __restrict__ Yf, int ldyf,
    u16* __restrict__ Yb, int ldyb,
    int K)
{
  __shared__ u16 As[64 * 32];
  __shared__ u16 Bs[64 * 32];
  const int t = threadIdx.x;
  const int m0 = blockIdx.y * 64, n0 = blockIdx.x * 64;
  const int r8 = t >> 2, c8 = (t & 3) * 8;
  const int lane = t & 63, w = t >> 6;
  const int cl = lane & 15, quad = lane >> 4;
  const int wm = (w >> 1) * 32, wn = (w & 1) * 32;

  f32x4 acc[2][2];
#pragma unroll
  for (int i = 0; i < 2; ++i)
#pragma unroll
    for (int j = 0; j < 2; ++j) acc[i][j] = (f32x4){0.f, 0.f, 0.f, 0.f};

  for (int k0 = 0; k0 < K; k0 += 32) {
    const u16* ag = A + (size_t)(m0 + r8) * lda + k0 + c8;
    const u16* bg = W + (size_t)(n0 + r8) * K + k0 + c8;
    __syncthreads();
    glds16(ag, &As[t * 8]);
    glds16(bg, &Bs[t * 8]);
    __syncthreads();

    short8 af[2], bfr[2];
#pragma unroll
    for (int i = 0; i < 2; ++i)
      af[i] = *(const short8*)&As[(wm + i * 16 + cl) * 32 + quad * 8];
#pragma unroll
    for (int j = 0; j < 2; ++j)
      bfr[j] = *(const short8*)&Bs[(wn + j * 16 + cl) * 32 + quad * 8];
#pragma unroll
    for (int mt = 0; mt < 2; ++mt)
#pragma unroll
      for (int nt = 0; nt < 2; ++nt)
        acc[mt][nt] = __builtin_amdgcn_mfma_f32_16x16x32_bf16(
            af[mt], bfr[nt], acc[mt][nt], 0, 0, 0);
  }

#pragma unroll
  for (int mt = 0; mt < 2; ++mt)
#pragma unroll
    for (int nt = 0; nt < 2; ++nt) {
      const int colg = n0 + wn + nt * 16 + cl;
      const float bs = bias[colg];
#pragma unroll
      for (int r = 0; r < 4; ++r) {
        const int rowg = m0 + wm + mt * 16 + quad * 4 + r;
        float v = acc[mt][nt][r] + bs;
        if (resb) v += bf2f(resb[(size_t)rowg * ldrb + colg]);
        if (Yf) Yf[(size_t)rowg * ldyf + colg] = v;
        if (Yb) Yb[(size_t)rowg * ldyb + colg] = f2bf(v);
      }
    }
}

// ---------------------------------------------------------------------------
// Weight fusion: W1f[n][k] = k<256 ? W1[n][k] : sum_m W1[n][256+m]*Wo[m][k-256]
// b1f[n] = b1[n] + sum_m W1[n][256+m]*bo[m].  All fp32 math, bf16 output.
// grid (512, 2): y=0 self, y=1 cross. Block = 256 threads, one n-row each.
// ---------------------------------------------------------------------------
__global__ __launch_bounds__(256) void wfuse_kernel(
    const float* __restrict__ W1, const float* __restrict__ Wo,
    const float* __restrict__ b1, const float* __restrict__ bo,
    const float* __restrict__ cW1, const float* __restrict__ cWo,
    const float* __restrict__ cb1, const float* __restrict__ cbo,
    u16* __restrict__ W1f, u16* __restrict__ cW1f,
    float* __restrict__ b1f, float* __restrict__ cb1f)
{
  const int n = blockIdx.x, sel = blockIdx.y;
  const float* Ws = sel ? cW1 : W1;
  const float* Wos = sel ? cWo : Wo;
  u16* out = sel ? cW1f : W1f;
  __shared__ float rowh[256];
  const int t = threadIdx.x;
  rowh[t] = Ws[(size_t)n * 512 + 256 + t];
  out[(size_t)n * 512 + t] = f2bf(Ws[(size_t)n * 512 + t]);
  __syncthreads();
  float acc = 0.f;
  for (int m = 0; m < 256; ++m) acc += rowh[m] * Wos[(size_t)m * 256 + t];
  out[(size_t)n * 512 + 256 + t] = f2bf(acc);
  if (t == 0) {
    const float* bos = sel ? cbo : bo;
    const float* b1s = sel ? cb1 : b1;
    float a = b1s[n];
    for (int m = 0; m < 256; ++m) a += rowh[m] * bos[m];
    (sel ? cb1f : b1f)[n] = a;
  }
}

// ---------------------------------------------------------------------------
// RoPE batched. qkv (M2,768) -> Qu (scaled 0.125*log2e), Ku, Vu bf16 (M2,256).
// ---------------------------------------------------------------------------
__global__ __launch_bounds__(256) void rope_repack_kernel(
    const u16* __restrict__ qkv, const float* __restrict__ enc0,
    const float* __restrict__ enc1,
    u16* __restrict__ Q, u16* __restrict__ K, u16* __restrict__ V)
{
  const int idx = blockIdx.x * blockDim.x + threadIdx.x;  // < M2*4*32
  const int i = idx & 31;
  const int h = (idx >> 5) & 3;
  const int m = idx >> 7;
  const int half = m >> 13;
  const int lm = m & (MROWS - 1);
  const float* enc = half ? enc1 : enc0;
  const u16* src = qkv + (size_t)m * 768 + h * 192 + i * 6;
  const unsigned a0 = *(const unsigned*)(src);
  const unsigned a1 = *(const unsigned*)(src + 2);
  const unsigned a2 = *(const unsigned*)(src + 4);
  const float q0 = bf2f((u16)a0), k0 = bf2f((u16)(a0 >> 16));
  const float v0 = bf2f((u16)a1), q1 = bf2f((u16)(a1 >> 16));
  const float k1 = bf2f((u16)a2), v1 = bf2f((u16)(a2 >> 16));
  const float c = enc[(size_t)lm * 64 + 2 * i];
  const float s = enc[(size_t)MROWS * 64 + (size_t)lm * 64 + 2 * i];
  const float QSC = 0.18033688011112042f;   // 0.125 * log2(e) -> exp2 softmax
  const size_t o = (size_t)m * 256 + h * 64 + 2 * i;
  *(unsigned*)(Q + o) = (unsigned)f2bf((q0 * c - q1 * s) * QSC) |
                        ((unsigned)f2bf((q1 * c + q0 * s) * QSC) << 16);
  *(unsigned*)(K + o) = (unsigned)f2bf(k0 * c - k1 * s) |
                        ((unsigned)f2bf(k1 * c + k0 * s) << 16);
  *(unsigned*)(V + o) = (unsigned)f2bf(v0) | ((unsigned)f2bf(v1) << 16);
}

// bf16 unheads (M2,256) -> bf16 transposed head-major (8,H,64,2048)
__global__ __launch_bounds__(256) void transpose_v_kernel(
    const u16* __restrict__ in, u16* __restrict__ out)
{
  __shared__ u16 Tl[64][72];
  const int bz = blockIdx.z, h = blockIdx.y;
  const int n0 = blockIdx.x * 64;
  const int t = threadIdx.x;
  {
    const int row = t >> 2, c16 = (t & 3) * 16;
    const u16* src = in + (size_t)(bz * NTOK + n0 + row) * 256 + h * 64 + c16;
    *(uint4*)&Tl[row][c16] = *(const uint4*)src;
    *(uint4*)&Tl[row][c16 + 8] = *(const uint4*)(src + 8);
  }
  __syncthreads();
  const int d = t >> 2, qr = t & 3;
  union { u16 u[16]; uint4 v[2]; } pk;
#pragma unroll
  for (int j = 0; j < 16; ++j) pk.u[j] = Tl[qr * 16 + j][d];
  u16* dst = out + ((size_t)((bz * NHEAD + h) * 64 + d)) * NTOK + n0 + qr * 16;
  *(uint4*)dst = pk.v[0];
  *(uint4*)(dst + 8) = pk.v[1];
}

// ---------------------------------------------------------------------------
// MFMA flash attention (S^T form, exp2 softmax), 128-q blocks, 32 q/wave.
// ---------------------------------------------------------------------------
__global__ __launch_bounds__(256, 4) void attn3_kernel(
    const u16* __restrict__ Qb, const u16* __restrict__ Kb,
    const u16* __restrict__ Vtb,
    u16* __restrict__ Po, float* __restrict__ Pm, float* __restrict__ Pl,
    int cross)
{
  __shared__ u16 Ks[64 * 72];
  __shared__ u16 Vs[64 * 72];
  __shared__ u16 QPs[128 * 72];
  const int y = blockIdx.y, z = blockIdx.z;
  const int h2 = y >> 4, b = (y >> 2) & 3, h = y & 3;
  const int kh = cross ? (1 - h2) : h2;
  const int qrowbase = (h2 * 4 + b) * NTOK;
  const int krowbase = (kh * 4 + b) * NTOK + z * 1024;
  const int vz = kh * 4 + b;
  const int n0 = blockIdx.x * 128;
  const int t = threadIdx.x, lane = t & 63, w = t >> 6;
  const int cl = lane & 15, quad = lane >> 4;

  {
    const int row = t >> 1, c32 = (t & 1) * 32;
    const u16* src = Qb + (size_t)(qrowbase + n0 + row) * 256 + h * 64 + c32;
    uint4 v0 = *(const uint4*)src;
    uint4 v1 = *(const uint4*)(src + 8);
    uint4 v2 = *(const uint4*)(src + 16);
    uint4 v3 = *(const uint4*)(src + 24);
    u16* d = &QPs[row * 72 + c32];
    *(uint4*)d = v0; *(uint4*)(d + 8) = v1;
    *(uint4*)(d + 16) = v2; *(uint4*)(d + 24) = v3;
  }
  __syncthreads();
  const int q0 = w * 32;
  short8 bq[2][2];
#pragma unroll
  for (int c = 0; c < 2; ++c) {
    bq[c][0] = *(const short8*)&QPs[(q0 + c * 16 + cl) * 72 + quad * 8];
    bq[c][1] = *(const short8*)&QPs[(q0 + c * 16 + cl) * 72 + quad * 8 + 32];
  }

  float m_r[2] = {-1e30f, -1e30f}, l_r[2] = {0.f, 0.f};
  f32x4 o[2][4];
#pragma unroll
  for (int c = 0; c < 2; ++c)
#pragma unroll
    for (int i = 0; i < 4; ++i) o[c][i] = (f32x4){0.f, 0.f, 0.f, 0.f};

  const int srow = t >> 2, sc16 = (t & 3) * 16;
  const u16* Kg = Kb + (size_t)(krowbase + srow) * 256 + h * 64 + sc16;
  const u16* Vg = Vtb + ((size_t)(vz * NHEAD + h) * 64 + srow) * NTOK + z * 1024 + sc16;
  uint4 ka0 = *(const uint4*)Kg, ka1 = *(const uint4*)(Kg + 8);
  uint4 va0 = *(const uint4*)Vg, va1 = *(const uint4*)(Vg + 8);

  for (int tile = 0; tile < 16; ++tile) {
    __syncthreads();
    *(uint4*)&Ks[srow * 72 + sc16] = ka0;
    *(uint4*)&Ks[srow * 72 + sc16 + 8] = ka1;
    *(uint4*)&Vs[srow * 72 + sc16] = va0;
    *(uint4*)&Vs[srow * 72 + sc16 + 8] = va1;
    __syncthreads();
    if (tile < 15) {
      Kg += 64 * 256; Vg += 64;
      ka0 = *(const uint4*)Kg; ka1 = *(const uint4*)(Kg + 8);
      va0 = *(const uint4*)Vg; va1 = *(const uint4*)(Vg + 8);
    }

    f32x4 sf[2][4];
#pragma unroll
    for (int kb = 0; kb < 4; ++kb) {
      short8 ak0 = *(const short8*)&Ks[(kb * 16 + cl) * 72 + quad * 8];
      short8 ak1 = *(const short8*)&Ks[(kb * 16 + cl) * 72 + quad * 8 + 32];
#pragma unroll
      for (int c = 0; c < 2; ++c) {
        f32x4 acc = (f32x4){0.f, 0.f, 0.f, 0.f};
        acc = __builtin_amdgcn_mfma_f32_16x16x32_bf16(ak0, bq[c][0], acc, 0, 0, 0);
        acc = __builtin_amdgcn_mfma_f32_16x16x32_bf16(ak1, bq[c][1], acc, 0, 0, 0);
        sf[c][kb] = acc;
      }
    }

#pragma unroll
    for (int c = 0; c < 2; ++c) {
      float mx = sf[c][0][0];
#pragma unroll
      for (int kb = 0; kb < 4; ++kb)
#pragma unroll
        for (int r = 0; r < 4; ++r) mx = fmaxf(mx, sf[c][kb][r]);
      mx = fmaxf(mx, __shfl_xor(mx, 16));
      mx = fmaxf(mx, __shfl_xor(mx, 32));
      const float mn = fmaxf(m_r[c], mx);
      const float alpha = exp2f(m_r[c] - mn);
      m_r[c] = mn;
      float rs = 0.f;
#pragma unroll
      for (int kb = 0; kb < 4; ++kb)
#pragma unroll
        for (int r = 0; r < 4; ++r) {
          const float p = exp2f(sf[c][kb][r] - mn);
          sf[c][kb][r] = p; rs += p;
        }
      rs += __shfl_xor(rs, 16);
      rs += __shfl_xor(rs, 32);
      l_r[c] = l_r[c] * alpha + rs;
#pragma unroll
      for (int db = 0; db < 4; ++db) o[c][db] *= alpha;
#pragma unroll
      for (int kb = 0; kb < 4; ++kb) {
        unsigned d0 = __builtin_amdgcn_perm(__float_as_uint(sf[c][kb][1]),
                                            __float_as_uint(sf[c][kb][0]), 0x07060302u);
        unsigned d1 = __builtin_amdgcn_perm(__float_as_uint(sf[c][kb][3]),
                                            __float_as_uint(sf[c][kb][2]), 0x07060302u);
        uint2 pk; pk.x = d0; pk.y = d1;
        *(uint2*)&QPs[(q0 + c * 16 + cl) * 72 + kb * 16 + quad * 4] = pk;
      }
    }

    short8 bp[2][2];
#pragma unroll
    for (int c = 0; c < 2; ++c) {
      bp[c][0] = *(const short8*)&QPs[(q0 + c * 16 + cl) * 72 + quad * 8];
      bp[c][1] = *(const short8*)&QPs[(q0 + c * 16 + cl) * 72 + quad * 8 + 32];
    }
#pragma unroll
    for (int db = 0; db < 4; ++db) {
      short8 av0 = *(const short8*)&Vs[(db * 16 + cl) * 72 + quad * 8];
      short8 av1 = *(const short8*)&Vs[(db * 16 + cl) * 72 + quad * 8 + 32];
#pragma unroll
      for (int c = 0; c < 2; ++c) {
        o[c][db] = __builtin_amdgcn_mfma_f32_16x16x32_bf16(av0, bp[c][0], o[c][db], 0, 0, 0);
        o[c][db] = __builtin_amdgcn_mfma_f32_16x16x32_bf16(av1, bp[c][1], o[c][db], 0, 0, 0);
      }
    }
  }

#pragma unroll
  for (int c = 0; c < 2; ++c) {
    const int rp = z * 65536 + y * 2048 + n0 + q0 + c * 16 + cl;
#pragma unroll
    for (int db = 0; db < 4; ++db) {
      ushort4 st;
      st.x = f2bf(o[c][db][0]); st.y = f2bf(o[c][db][1]);
      st.z = f2bf(o[c][db][2]); st.w = f2bf(o[c][db][3]);
      *(ushort4*)(Po + (size_t)rp * 64 + db * 16 + quad * 4) = st;
    }
    if (quad == 0) { Pm[rp] = m_r[c]; Pl[rp] = l_r[c]; }
  }
}

// combine the 2 K-split partials (exp2 domain) -> bf16 unheads output
__global__ __launch_bounds__(256) void attn_combine_kernel(
    const u16* __restrict__ Po, const float* __restrict__ Pm,
    const float* __restrict__ Pl, u16* __restrict__ Ou)
{
  const int rowi = blockIdx.x * 4 + (threadIdx.x >> 6);
  const int lane = threadIdx.x & 63;
  const float m0 = Pm[rowi], m1 = Pm[65536 + rowi];
  const float l0 = Pl[rowi], l1 = Pl[65536 + rowi];
  const float M = fmaxf(m0, m1);
  const float e0 = exp2f(m0 - M), e1 = exp2f(m1 - M);
  const float inv = 1.f / (e0 * l0 + e1 * l1);
  const float o0 = bf2f(Po[(size_t)rowi * 64 + lane]);
  const float o1 = bf2f(Po[(size_t)65536 * 64 + (size_t)rowi * 64 + lane]);
  const float val = (e0 * o0 + e1 * o1) * inv;
  const int y = rowi >> 11, q = rowi & 2047;
  const int bz = y >> 2, h = y & 3;
  Ou[(size_t)(bz * NTOK + q) * 256 + h * 64 + lane] = f2bf(val);
}

// ---------------------------------------------------------------------------
// LayerNorm + exact GELU, bf16 in (M2,512) -> bf16 out
// ---------------------------------------------------------------------------
__global__ __launch_bounds__(256) void ln_gelu_kernel(
    const u16* __restrict__ Hm, const float* __restrict__ g,
    const float* __restrict__ be, u16* __restrict__ out)
{
  const int rowi = blockIdx.x * 4 + (threadIdx.x >> 6);
  const int lane = threadIdx.x & 63;
  const u16* row = Hm + (size_t)rowi * 512 + lane * 8;
  u16* orow = out + (size_t)rowi * 512 + lane * 8;
  uint4 raw = *(const uint4*)row;
  float x[8];
  const unsigned* rw = (const unsigned*)&raw;
#pragma unroll
  for (int i = 0; i < 4; ++i) {
    x[2 * i]     = bf2f((u16)rw[i]);
    x[2 * i + 1] = bf2f((u16)(rw[i] >> 16));
  }
  float s = 0.f;
#pragma unroll
  for (int i = 0; i < 8; ++i) s += x[i];
#pragma unroll
  for (int off = 32; off; off >>= 1) s += __shfl_xor(s, off);
  const float mean = s * (1.f / 512.f);
  float s2 = 0.f;
#pragma unroll
  for (int i = 0; i < 8; ++i) { const float d = x[i] - mean; s2 += d * d; }
#pragma unroll
  for (int off = 32; off; off >>= 1) s2 += __shfl_xor(s2, off);
  const float rstd = rsqrtf(s2 * (1.f / 512.f) + 1e-5f);
  unsigned ov[4];
#pragma unroll
  for (int i = 0; i < 4; ++i) {
    const int c = lane * 8 + 2 * i;
    const float y0 = (x[2 * i] - mean) * rstd * g[c] + be[c];
    const float y1 = (x[2 * i + 1] - mean) * rstd * g[c + 1] + be[c + 1];
    const float g0 = 0.5f * y0 * (1.f + erff(y0 * 0.70710678118654752f));
    const float g1 = 0.5f * y1 * (1.f + erff(y1 * 0.70710678118654752f));
    ov[i] = (unsigned)f2bf(g0) | ((unsigned)f2bf(g1) << 16);
  }
  *(uint4*)orow = *(uint4*)ov;
}

// ---------------------------------------------------------------------------
// pack everything fp32 -> bf16: 5 weight mats (589824 elems) + 2 descs.
// ---------------------------------------------------------------------------
__global__ __launch_bounds__(256) void pack_all_kernel(
    const float* w0, const float* w1, const float* w2, const float* w3,
    const float* w4, const float* d0, const float* d1,
    u16* __restrict__ wb, u16* __restrict__ descb)
{
  const size_t idx4 = ((size_t)blockIdx.x * 256 + threadIdx.x) * 4;
  const float* src; u16* dst; size_t off;
  if (idx4 < 589824) {
    off = idx4; dst = wb + idx4;
    if      (idx4 < 196608) { src = w0; }
    else if (idx4 < 327680) { src = w1; off -= 196608; }
    else if (idx4 < 393216) { src = w2; off -= 327680; }
    else if (idx4 < 458752) { src = w3; off -= 393216; }
    else                    { src = w4; off -= 458752; }
  } else {
    size_t o = idx4 - 589824;
    dst = descb + o;
    if (o < NMu) { src = d0; off = o; }
    else         { src = d1; off = o - NMu; }
  }
  float4 v = *(const float4*)(src + off);
  ushort4 ov;
  ov.x = f2bf(v.x); ov.y = f2bf(v.y); ov.z = f2bf(v.z); ov.w = f2bf(v.w);
  *(ushort4*)dst = ov;
}

// ---------------------------------------------------------------------------
extern "C" void kernel_launch(void* const* d_in, const int* in_sizes, int n_in,
                              void* d_out, int out_size, void* d_ws, size_t ws_size,
                              hipStream_t stream) {
  const float* desc0  = (const float*)d_in[0];
  const float* desc1  = (const float*)d_in[1];
  const float* enc0   = (const float*)d_in[2];
  const float* enc1   = (const float*)d_in[3];
  const float* s_Wqkv = (const float*)d_in[4];
  const float* s_bqkv = (const float*)d_in[5];
  const float* s_Wout = (const float*)d_in[6];
  const float* s_bout = (const float*)d_in[7];
  const float* s_W1   = (const float*)d_in[8];
  const float* s_b1   = (const float*)d_in[9];
  const float* s_g    = (const float*)d_in[10];
  const float* s_be   = (const float*)d_in[11];
  const float* s_W2   = (const float*)d_in[12];
  const float* s_b2   = (const float*)d_in[13];
  const float* c_Wqk  = (const float*)d_in[14];
  const float* c_bqk  = (const float*)d_in[15];
  const float* c_Wv   = (const float*)d_in[16];
  const float* c_bv   = (const float*)d_in[17];
  const float* c_Wo   = (const float*)d_in[18];
  const float* c_bo   = (const float*)d_in[19];
  const float* c_W1   = (const float*)d_in[20];
  const float* c_b1   = (const float*)d_in[21];
  const float* c_g    = (const float*)d_in[22];
  const float* c_be   = (const float*)d_in[23];
  const float* c_W2   = (const float*)d_in[24];
  const float* c_b2   = (const float*)d_in[25];

  u16* U = (u16*)d_ws;
  u16* descb = U + 0 * NMu;             // [all]
  u16* qkvb  = U + 2 * NMu;             // 6u, phase A only
  u16* ctxb  = U + 2 * NMu;             // 2u, combine out (self B / cross E)
  u16* Qu    = U + 8 * NMu;             // self Q / cross qkb
  u16* Ku    = U + 10 * NMu;            // self K / cross vb
  u16* Vu    = U + 12 * NMu;            // self V staging
  u16* Vt    = U + 14 * NMu;            // transposed V
  u16* hbufb = U + 12 * NMu;            // 4u ffn hidden (after attn)
  u16* Po    = U + 16 * NMu;            // 4u attn partials
  u16* hb2   = U + 16 * NMu;            // 4u ln out (after combine)
  float* Pm  = (float*)(U + 20 * NMu);
  float* Pl  = Pm + 2 * 65536;
  float* b1f = Pl + 2 * 65536;          // 512 fp32
  float* cb1f = b1f + 512;
  u16* s_b   = U + 21 * NMu;            // self outputs
  u16* wb    = U + 23 * NMu;

  u16* Wqkvb = wb;                      // 196608
  u16* W2b   = wb + 196608;             // 131072
  u16* cQKVb = wb + 327680;             // cWqk(65536) || cWv(65536)
  u16* cW2b  = wb + 458752;             // 131072
  u16* W1f   = wb + 589824;             // 262144 (fused self FFN1 weight)
  u16* cW1f  = wb + 851968;             // 262144

  float* outf = (float*)d_out;

  const dim3 attn_grid(NTOK / 128, 32, 2);
  const dim3 tv_grid(NTOK / 64, NHEAD, 8);
  const int rope_blocks = (M2 * 128) / 256;
  const int lng_blocks  = M2 / 4;
  const int comb_blocks = 65536 / 4;
  const float BIG = 2.1e9f;   // nsplit sentinel handled via int
  (void)BIG;
  const float csc = 0.42466090014400953f;  // 8^-0.5 * sqrt(log2 e)

  // 1. pack weights + descs
  hipLaunchKernelGGL(pack_all_kernel, dim3(4672), dim3(256), 0, stream,
                     s_Wqkv, s_W2, c_Wqk, c_Wv, c_W2, desc0, desc1, wb, descb);
  // 2. fold Wout->W1, cWo->cW1 (+bias folds)
  hipLaunchKernelGGL(wfuse_kernel, dim3(512, 2), dim3(256), 0, stream,
                     s_W1, s_Wout, s_b1, s_bout, c_W1, c_Wo, c_b1, c_bo,
                     W1f, cW1f, b1f, cb1f);

  // ---------------- self blocks (batched) ----------------
  // 3. qkv GEMM
  hipLaunchKernelGGL(gemm_bf16_kernel, dim3(6, 128), dim3(256), 0, stream,
                     descb, 256, (const u16*)nullptr, 0, 1 << 30, Wqkvb,
                     s_bqkv, (const float*)nullptr, 1 << 30, 1.f, 1.f,
                     qkvb, 768, (u16*)nullptr, 0, 256);
  // 4. rope
  hipLaunchKernelGGL(rope_repack_kernel, dim3(rope_blocks), dim3(256), 0, stream,
                     qkvb, enc0, enc1, Qu, Ku, Vu);
  // 5. transpose V
  hipLaunchKernelGGL(transpose_v_kernel, tv_grid, dim3(256), 0, stream, Vu, Vt);
  // 6/7. attention + combine
  hipLaunchKernelGGL(attn3_kernel, attn_grid, dim3(256), 0, stream,
                     Qu, Ku, Vt, Po, Pm, Pl, 0);
  hipLaunchKernelGGL(attn_combine_kernel, dim3(comb_blocks), dim3(256), 0, stream,
                     Po, Pm, Pl, ctxb);
  // 8. FFN1 (fused Wout): A=[descb | ctxb] @ W1f^T + b1f
  hipLaunchKernelGGL(gemm_bf16_kernel, dim3(4, 128), dim3(256), 0, stream,
                     descb, 256, ctxb, 256, 256, W1f,
                     b1f, (const float*)nullptr, 1 << 30, 1.f, 1.f,
                     hbufb, 512, (u16*)nullptr, 0, 512);
  // 9. LN + GELU
  hipLaunchKernelGGL(ln_gelu_kernel, dim3(lng_blocks), dim3(256), 0, stream,
                     hbufb, s_g, s_be, hb2);
  // 10. W2 + residual
  hipLaunchKernelGGL(gemm64_kernel, dim3(4, 256), dim3(256), 0, stream,
                     hb2, 512, W2b, s_b2, descb, 256,
                     (float*)nullptr, 0, s_b, 256, 512);

  // ---------------- cross block (batched) ----------------
  u16* qkb = Qu;
  u16* vb  = Ku;
  // 11. fused qk|v projection (per-half bias/scale/output)
  hipLaunchKernelGGL(gemm_bf16_kernel, dim3(4, 128), dim3(256), 0, stream,
                     s_b, 256, (const u16*)nullptr, 0, 1 << 30, cQKVb,
                     c_bqk, c_bv, 256, csc, 1.f,
                     qkb, 256, vb, 256, 256);
  // 12. transpose V
  hipLaunchKernelGGL(transpose_v_kernel, tv_grid, dim3(256), 0, stream, vb, Vt);
  // 13/14. attention + combine
  hipLaunchKernelGGL(attn3_kernel, attn_grid, dim3(256), 0, stream,
                     qkb, qkb, Vt, Po, Pm, Pl, 1);
  hipLaunchKernelGGL(attn_combine_kernel, dim3(comb_blocks), dim3(256), 0, stream,
                     Po, Pm, Pl, ctxb);
  // 15. FFN1 (fused cWo)
  hipLaunchKernelGGL(gemm_bf16_kernel, dim3(4, 128), dim3(256), 0, stream,
                     s_b, 256, ctxb, 256, 256, cW1f,
                     cb1f, (const float*)nullptr, 1 << 30, 1.f, 1.f,
                     hbufb, 512, (u16*)nullptr, 0, 512);
  // 16. LN + GELU
  hipLaunchKernelGGL(ln_gelu_kernel, dim3(lng_blocks), dim3(256), 0, stream,
                     hbufb, c_g, c_be, hb2);
  // 17. W2 + residual -> fp32 output
  hipLaunchKernelGGL(gemm64_kernel, dim3(4, 256), dim3(256), 0, stream,
                     hb2, 512, cW2b, c_b2, s_b, 256,
                     outf, 256, (u16*)nullptr, 0, 512);
}